// Round 2
// baseline (404.001 us; speedup 1.0000x reference)
//
#include <hip/hip_runtime.h>
#include <cmath>

#define T_TOK 2048
#define D_EMB 768
#define H_FFN 1536
#define NE    16
#define NPAIR (T_TOK * 4)

typedef __attribute__((ext_vector_type(8))) short          short8;
typedef __attribute__((ext_vector_type(8))) unsigned short ushort8;
typedef __attribute__((ext_vector_type(4))) unsigned short ushort4v;
typedef __attribute__((ext_vector_type(4))) float          floatx4;

__device__ __forceinline__ float bf2f(unsigned short u) {
  union { unsigned int i; float f; } v; v.i = ((unsigned int)u) << 16; return v.f;
}
__device__ __forceinline__ unsigned short f2bf(float f) {
  union { float f; unsigned int i; } v; v.f = f;
  unsigned int r = v.i + 0x7fffu + ((v.i >> 16) & 1u);   // RNE
  return (unsigned short)(r >> 16);
}

// async global->LDS, 16B per lane. LDS dest is wave-uniform base + lane*16.
__device__ __forceinline__ void gload16(const unsigned short* g, unsigned short* l) {
  __builtin_amdgcn_global_load_lds(
      (const __attribute__((address_space(1))) unsigned int*)g,
      (__attribute__((address_space(3))) unsigned int*)l,
      16, 0, 0);
}

// ---------------- K0: dtype sniff (1 = inputs are bf16) ---------------------
__global__ __launch_bounds__(64) void sniff_kernel(
    const unsigned int* __restrict__ x, int* __restrict__ flag)
{
  int lane = threadIdx.x;
  int c = 0;
  for (int i = 0; i < 8; i++) {
    unsigned int w = x[i * 64 + lane];
    unsigned int e = (w >> 7) & 0xFFu;
    c += (e >= 100u && e <= 140u) ? 1 : 0;
  }
  for (int off = 32; off > 0; off >>= 1) c += __shfl_down(c, off);
  if (lane == 0) *flag = (c > 300) ? 1 : 0;
}

// ---------------- K0b: f32 -> bf16 for x + small vectors (f32 mode only) ----
__global__ __launch_bounds__(256) void conv_kernel(
    const float* __restrict__ x, const float* __restrict__ fc1b,
    const float* __restrict__ lnw, const float* __restrict__ lnb,
    const float* __restrict__ fc2b,
    unsigned short* __restrict__ dx, unsigned short* __restrict__ dfc1b,
    unsigned short* __restrict__ dlnw, unsigned short* __restrict__ dlnb,
    unsigned short* __restrict__ dfc2b, const int* __restrict__ flag)
{
  if (*flag) return;
  int g = blockIdx.x * 256 + threadIdx.x;          // grid 2048*256 = 524288
#pragma unroll
  for (int i = 0; i < 3; i++) dx[g + i * 524288] = f2bf(x[g + i * 524288]);
  if (g < 24576) { dfc1b[g] = f2bf(fc1b[g]); dlnw[g] = f2bf(lnw[g]); dlnb[g] = f2bf(lnb[g]); }
  if (g < 12288) dfc2b[g] = f2bf(fc2b[g]);
}

// ---------------- K0c: weight transpose [e][R][C] -> [e][C][R] bf16 ---------
template<int R, int C>
__global__ __launch_bounds__(256) void transpose_kernel(
    const unsigned short* __restrict__ srcB, const float* __restrict__ srcF,
    const int* __restrict__ flag, unsigned short* __restrict__ dst)
{
  __shared__ __align__(16) unsigned short tile[64][72];
  constexpr int RT = R / 64, CT = C / 64;
  int bx  = blockIdx.x;
  int e   = bx / (RT * CT);
  int rem = bx % (RT * CT);
  int rt  = rem / CT, ct = rem % CT;
  int tid = threadIdx.x;
  int r   = tid >> 2;
  int c   = (tid & 3) * 16;
  int xr  = (r & 7) * 8;                       // XOR swizzle per row
  size_t sbase = ((size_t)e * R + rt * 64 + r) * C + ct * 64 + c;
  if (*flag) {
    ushort8 v0 = *(const ushort8*)(srcB + sbase);
    ushort8 v1 = *(const ushort8*)(srcB + sbase + 8);
    *(ushort8*)&tile[r][(c) ^ xr]     = v0;
    *(ushort8*)&tile[r][(c + 8) ^ xr] = v1;
  } else {
    unsigned short tmp[16];
#pragma unroll
    for (int q = 0; q < 4; q++) {
      floatx4 f = *(const floatx4*)(srcF + sbase + q * 4);
#pragma unroll
      for (int j = 0; j < 4; j++) tmp[q * 4 + j] = f2bf(f[j]);
    }
    *(ushort8*)&tile[r][(c) ^ xr]     = *(ushort8*)&tmp[0];
    *(ushort8*)&tile[r][(c + 8) ^ xr] = *(ushort8*)&tmp[8];
  }
  __syncthreads();
  int n  = tid >> 2;
  int k  = (tid & 3) * 16;
  unsigned short outv[16];
#pragma unroll
  for (int j = 0; j < 16; j++) {
    int kr = k + j;
    outv[j] = tile[kr][n ^ ((kr & 7) * 8)];
  }
  size_t dbase = ((size_t)e * C + ct * 64 + n) * R + rt * 64 + k;
  *(ushort8*)(dst + dbase)     = *(ushort8*)&outv[0];
  *(ushort8*)(dst + dbase + 8) = *(ushort8*)&outv[8];
}

// ---------------- K1: gating, wave-parallel, ZERO atomics -------------------
__global__ __launch_bounds__(64) void gate_kernel(
    const unsigned short* __restrict__ x16, const float* __restrict__ x32,
    const unsigned short* __restrict__ gw16, const float* __restrict__ gw32,
    const unsigned short* __restrict__ gb16, const float* __restrict__ gb32,
    const int* __restrict__ flag,
    int* __restrict__ psel, float* __restrict__ pw)
{
  int t = blockIdx.x;
  int lane = threadIdx.x;
  int isbf = *flag;
  float acc[NE];
#pragma unroll
  for (int e = 0; e < NE; e++) acc[e] = 0.f;
  if (isbf) {
#pragma unroll
    for (int i = 0; i < D_EMB / 64; i++) {
      int d = i * 64 + lane;
      float xv = bf2f(x16[(size_t)t * D_EMB + d]);
      ushort8 g0 = *(const ushort8*)(gw16 + d * NE);
      ushort8 g1 = *(const ushort8*)(gw16 + d * NE + 8);
#pragma unroll
      for (int e = 0; e < 8; e++) acc[e]     += xv * bf2f(g0[e]);
#pragma unroll
      for (int e = 0; e < 8; e++) acc[8 + e] += xv * bf2f(g1[e]);
    }
  } else {
#pragma unroll
    for (int i = 0; i < D_EMB / 64; i++) {
      int d = i * 64 + lane;
      float xv = x32[(size_t)t * D_EMB + d];
#pragma unroll
      for (int q = 0; q < 4; q++) {
        floatx4 g = *(const floatx4*)(gw32 + d * NE + q * 4);
#pragma unroll
        for (int j = 0; j < 4; j++) acc[q * 4 + j] += xv * g[j];
      }
    }
  }
  __shared__ __align__(16) float sacc[64][NE + 1];
#pragma unroll
  for (int e = 0; e < NE; e++) sacc[lane][e] = acc[e];
  __syncthreads();
  int e = lane & 15, q = lane >> 4;
  float s = 0.f;
#pragma unroll
  for (int i = 0; i < 16; i++) s += sacc[q * 16 + i][e];
  s += __shfl_xor(s, 16);
  s += __shfl_xor(s, 32);
  float sv = s + (isbf ? bf2f(gb16[e]) : gb32[e]);
  if (e == 0) sv = -1e9f;
  float m = sv;
#pragma unroll
  for (int off = 8; off > 0; off >>= 1) m = fmaxf(m, __shfl_xor(m, off));
  float pe = expf(sv - m);
  float den = pe;
#pragma unroll
  for (int off = 8; off > 0; off >>= 1) den += __shfl_xor(den, off);
  float pr = pe / den;
  float val = (e == 0) ? -1.f : pr;
  int sel0, sel1, sel2; float sw0, sw1, sw2;
#pragma unroll
  for (int k = 0; k < 3; k++) {
    float bv = val; int bi = e;
#pragma unroll
    for (int off = 8; off > 0; off >>= 1) {
      float ov = __shfl_xor(bv, off);
      int   oi = __shfl_xor(bi, off);
      if (ov > bv || (ov == bv && oi < bi)) { bv = ov; bi = oi; }
    }
    if (k == 0) { sel0 = bi; sw0 = bv; }
    else if (k == 1) { sel1 = bi; sw1 = bv; }
    else { sel2 = bi; sw2 = bv; }
    if (e == bi) val = -1.f;
  }
  if (lane == 0) {
    psel[t * 4] = 0;    pw[t * 4] = 1.0f;
    psel[t * 4 + 1] = sel0; pw[t * 4 + 1] = sw0;
    psel[t * 4 + 2] = sel1; pw[t * 4 + 2] = sw1;
    psel[t * 4 + 3] = sel2; pw[t * 4 + 3] = sw2;
  }
}

// ---------------- K1b: deterministic per-expert compaction (no atomics) -----
__global__ __launch_bounds__(256) void bucket_kernel(
    const int* __restrict__ psel, int* __restrict__ cnt, int* __restrict__ plist)
{
  int e = blockIdx.x;
  int tid = threadIdx.x;
  int wave = tid >> 6, lane = tid & 63;
  __shared__ int wsum[4];
  __shared__ int base;
  if (tid == 0) base = 0;
  __syncthreads();
  for (int c0 = 0; c0 < NPAIR; c0 += 256) {
    bool mt = (psel[c0 + tid] == e);
    unsigned long long mask = __ballot(mt);
    int wcount = __popcll(mask);
    if (lane == 0) wsum[wave] = wcount;
    __syncthreads();
    int wpre = 0;
#pragma unroll
    for (int w = 0; w < 4; w++) if (w < wave) wpre += wsum[w];
    int total = wsum[0] + wsum[1] + wsum[2] + wsum[3];
    if (mt) {
      int off = __popcll(mask & ((1ULL << lane) - 1ULL));
      plist[e * T_TOK + base + wpre + off] = c0 + tid;
    }
    __syncthreads();
    if (tid == 0) base += total;
    __syncthreads();
  }
  if (tid == 0) cnt[e] = base;
}

// ---------------- K2/K4: grouped GEMM, 2-phase double-buffered pipeline -----
// Block tile 128x128, BK=64. 4 waves as 2x2 -> wave tile 64x64.
// Staging via global_load_lds (16B/lane, per-lane gathered source, linear LDS
// dest), XOR chunk swizzle on BOTH source address and ds_read side.
// Double-buffered: tile t+1's loads are issued BEFORE computing tile t, so
// HBM/L2 latency hides under the 16 ds_read + 32 MFMA of the current tile.
template<int KDIM, int NDIM, bool GELU, bool HASBIAS, bool AROWDIV4, bool OUTF32>
__global__ __launch_bounds__(256) void moe_gemm(
    const unsigned short* __restrict__ AO, const unsigned short* __restrict__ AC,
    const unsigned short* __restrict__ BT,       // [e][NDIM][KDIM]
    const unsigned short* __restrict__ biasO, const unsigned short* __restrict__ biasC,
    const int* __restrict__ flag,
    const int* __restrict__ cnt, const int* __restrict__ plist,
    unsigned short* __restrict__ outB, float* __restrict__ outF)
{
  const int NSP = NDIM / 128;
  int bx  = blockIdx.x;
  int e   = bx / (16 * NSP);
  int rem = bx % (16 * NSP);
  int mt  = rem / NSP;
  int ns  = rem % NSP;
  int count = cnt[e];
  if (mt * 128 >= count) return;
  const unsigned short* Abase   = (*flag) ? AO : AC;
  const unsigned short* biasAll = (*flag) ? biasO : biasC;

  // Double-buffered linear tiles (required by global_load_lds), 16 KB each.
  __shared__ __align__(16) unsigned short sA[2][128 * 64];
  __shared__ __align__(16) unsigned short sB[2][128 * 64];
  __shared__ int sp[128];

  int tid = threadIdx.x;
  if (tid < 128) {
    int rg  = mt * 128 + tid;
    int idx = rg < count ? rg : count - 1;    // duplicate last row (pad)
    sp[tid] = plist[e * T_TOK + idx];
  }
  __syncthreads();

  int lane = tid & 63;
  int wave = tid >> 6;
  int n0   = ns * 128;

  // --- staging addresses: wave w stages A rows [w*32,w*32+32) and B rows ---
  // ditto, as 4 chunks of 8 rows each. Within a chunk, lane i covers
  // row base+(i>>3), LDS 16B-slot (i&7); source k-chunk = (i&7)^(i>>3).
  int lrow  = lane >> 3;                       // 0..7
  int lsch  = (lane & 7) ^ lrow;               // swizzled source chunk
  const unsigned short* ag[4];
  const unsigned short* bg[4];
  int loff[4];
#pragma unroll
  for (int s = 0; s < 4; s++) {
    int r  = wave * 32 + s * 8;                // chunk base row (local)
    int p  = sp[r + lrow];
    ag[s] = Abase + (size_t)(AROWDIV4 ? (p >> 2) : p) * KDIM + lsch * 8;
    bg[s] = BT + ((size_t)e * NDIM + n0 + r + lrow) * KDIM + lsch * 8;
    loff[s] = r * 64;                          // wave-uniform LDS base (shorts)
  }

  int m16  = lane & 15;
  int quad = lane >> 4;
  int wm   = (wave >> 1) * 64;
  int wn   = (wave & 1) * 64;
  int rsw  = (m16 & 7);                        // read-side XOR (row&7)

  floatx4 acc[4][4];
#pragma unroll
  for (int i = 0; i < 4; i++)
#pragma unroll
    for (int j = 0; j < 4; j++) acc[i][j] = (floatx4){0.f, 0.f, 0.f, 0.f};

  const int NT = KDIM / 64;
  // prologue: stage tile 0 into buffer 0, drain, barrier
#pragma unroll
  for (int s = 0; s < 4; s++) gload16(ag[s], &sA[0][loff[s]]);
#pragma unroll
  for (int s = 0; s < 4; s++) gload16(bg[s], &sB[0][loff[s]]);
  __syncthreads();

  int cur = 0;
  for (int t = 0; t < NT; ++t) {
    if (t + 1 < NT) {                          // issue next tile's loads NOW
      int k1 = (t + 1) * 64;
#pragma unroll
      for (int s = 0; s < 4; s++) gload16(ag[s] + k1, &sA[cur ^ 1][loff[s]]);
#pragma unroll
      for (int s = 0; s < 4; s++) gload16(bg[s] + k1, &sB[cur ^ 1][loff[s]]);
    }
#pragma unroll
    for (int ks = 0; ks < 2; ks++) {
      int ch = ((ks * 4 + quad) ^ rsw) * 8;    // swizzled k-chunk (shorts)
      short8 af[4], bf[4];
#pragma unroll
      for (int m = 0; m < 4; m++)
        af[m] = *(const short8*)(&sA[cur][0] + (wm + m * 16 + m16) * 64 + ch);
#pragma unroll
      for (int n = 0; n < 4; n++)
        bf[n] = *(const short8*)(&sB[cur][0] + (wn + n * 16 + m16) * 64 + ch);
#pragma unroll
      for (int m = 0; m < 4; m++)
#pragma unroll
        for (int n = 0; n < 4; n++)
          acc[m][n] = __builtin_amdgcn_mfma_f32_16x16x32_bf16(af[m], bf[n], acc[m][n], 0, 0, 0);
    }
    __syncthreads();                           // drains vmcnt: next buf ready,
    cur ^= 1;                                  // and prev-buf reads complete
  }

  // epilogue: C/D col = lane&15 (-> n dim), row = quad*4 + reg (-> m dim)
#pragma unroll
  for (int m = 0; m < 4; m++) {
#pragma unroll
    for (int r = 0; r < 4; r++) {
      int row_local = wm + m * 16 + quad * 4 + r;
      int rg = mt * 128 + row_local;
      if (rg < count) {
        int p = sp[row_local];
#pragma unroll
        for (int n = 0; n < 4; n++) {
          int col = n0 + wn + n * 16 + m16;
          float v = acc[m][n][r];
          if (HASBIAS) v += bf2f(biasAll[e * NDIM + col]);
          if (GELU)    v = 0.5f * v * (1.f + erff(v * 0.70710678118654752f));
          if (OUTF32) outF[(size_t)p * NDIM + col] = v;
          else        outB[(size_t)p * NDIM + col] = f2bf(v);
        }
      }
    }
  }
}

// ---------------- K3: LayerNorm per pair, combine weight folded in ----------
__global__ __launch_bounds__(256) void ln_kernel(
    unsigned short* __restrict__ Hbuf,
    const unsigned short* __restrict__ lnwO, const unsigned short* __restrict__ lnwC,
    const unsigned short* __restrict__ lnbO, const unsigned short* __restrict__ lnbC,
    const int* __restrict__ psel, const float* __restrict__ pw,
    const int* __restrict__ flag)
{
  int p = blockIdx.x;
  int tid = threadIdx.x;
  int e = psel[p];
  int isbf = *flag;
  const unsigned short* lnw = isbf ? lnwO : lnwC;
  const unsigned short* lnb = isbf ? lnbO : lnbC;
  unsigned short* hr = Hbuf + (size_t)p * H_FFN;
  bool act = tid < 192;
  float v[8];
  float s = 0.f, sq = 0.f;
  if (act) {
    ushort8 hv = *(const ushort8*)(hr + tid * 8);
#pragma unroll
    for (int j = 0; j < 8; j++) { v[j] = bf2f(hv[j]); s += v[j]; sq += v[j] * v[j]; }
  }
#pragma unroll
  for (int off = 32; off > 0; off >>= 1) {
    s  += __shfl_down(s, off);
    sq += __shfl_down(sq, off);
  }
  __shared__ float red[8];
  int wave = tid >> 6, lane = tid & 63;
  if (lane == 0) { red[wave * 2] = s; red[wave * 2 + 1] = sq; }
  __syncthreads();
  __shared__ float mv[2];
  if (tid == 0) {
    float S = 0.f, Q = 0.f;
    for (int w = 0; w < 4; w++) { S += red[w * 2]; Q += red[w * 2 + 1]; }
    float mu  = S * (1.f / H_FFN);
    float var = Q * (1.f / H_FFN) - mu * mu;
    mv[0] = mu; mv[1] = rsqrtf(var + 1e-5f);
  }
  __syncthreads();
  if (act) {
    float mu = mv[0], rstd = mv[1];
    float w = pw[p];
    ushort8 lw = *(const ushort8*)(lnw + e * H_FFN + tid * 8);
    ushort8 lb = *(const ushort8*)(lnb + e * H_FFN + tid * 8);
    ushort8 o;
#pragma unroll
    for (int j = 0; j < 8; j++)
      o[j] = f2bf(((v[j] - mu) * rstd * bf2f(lw[j]) + bf2f(lb[j])) * w);
    *(ushort8*)(hr + tid * 8) = o;
  }
}

// ---------------- K5: sum 4 pair outputs + weighted fc2 bias ----------------
__global__ __launch_bounds__(256) void combine_kernel(
    const float* __restrict__ Y,
    const unsigned short* __restrict__ b2O, const unsigned short* __restrict__ b2C,
    const int* __restrict__ psel, const float* __restrict__ pw,
    unsigned short* __restrict__ out16, float* __restrict__ out32,
    const int* __restrict__ flag)
{
  int t = blockIdx.x;
  int tid = threadIdx.x;
  if (tid >= 192) return;
  int isbf = *flag;
  const unsigned short* b2 = isbf ? b2O : b2C;
  int e1 = psel[t * 4 + 1], e2 = psel[t * 4 + 2], e3 = psel[t * 4 + 3];
  float w1 = pw[t * 4 + 1], w2 = pw[t * 4 + 2], w3 = pw[t * 4 + 3];
  int d = tid * 4;
  const float* Yb = Y + (size_t)t * 4 * D_EMB + d;
  floatx4 y0 = *(const floatx4*)(Yb);
  floatx4 y1 = *(const floatx4*)(Yb + D_EMB);
  floatx4 y2 = *(const floatx4*)(Yb + 2 * D_EMB);
  floatx4 y3 = *(const floatx4*)(Yb + 3 * D_EMB);
  ushort4v b0 = *(const ushort4v*)(b2 + d);
  ushort4v bb1 = *(const ushort4v*)(b2 + e1 * D_EMB + d);
  ushort4v bb2 = *(const ushort4v*)(b2 + e2 * D_EMB + d);
  ushort4v bb3 = *(const ushort4v*)(b2 + e3 * D_EMB + d);
  if (isbf) {
    ushort4v o;
#pragma unroll
    for (int j = 0; j < 4; j++) {
      float a = y0[j] + y1[j] + y2[j] + y3[j] + bf2f(b0[j])
              + w1 * bf2f(bb1[j]) + w2 * bf2f(bb2[j]) + w3 * bf2f(bb3[j]);
      o[j] = f2bf(a);
    }
    *(ushort4v*)(out16 + (size_t)t * D_EMB + d) = o;
  } else {
    floatx4 o;
#pragma unroll
    for (int j = 0; j < 4; j++)
      o[j] = y0[j] + y1[j] + y2[j] + y3[j] + bf2f(b0[j])
           + w1 * bf2f(bb1[j]) + w2 * bf2f(bb2[j]) + w3 * bf2f(bb3[j]);
    *(floatx4*)(out32 + (size_t)t * D_EMB + d) = o;
  }
}

extern "C" void kernel_launch(void* const* d_in, const int* in_sizes, int n_in,
                              void* d_out, int out_size, void* d_ws, size_t ws_size,
                              hipStream_t stream)
{
  (void)in_sizes; (void)n_in; (void)out_size; (void)ws_size;
  char* ws = (char*)d_ws;
  int*   cnt   = (int*)ws;                                 // 16 ints
  int*   plist = (int*)(ws + 256);                         // 16*2048 ints
  int*   psel  = (int*)(ws + 131328);                      // 8192 ints
  float* pw    = (float*)(ws + 164096);                    // 8192 f32
  int*   flag  = (int*)(ws + 196864);
  unsigned short* fc1bC = (unsigned short*)(ws + 197120);  // 24576 bf16
  unsigned short* lnwC  = (unsigned short*)(ws + 246272);
  unsigned short* lnbC  = (unsigned short*)(ws + 295424);
  unsigned short* fc2bC = (unsigned short*)(ws + 344576);  // 12288 bf16
  unsigned short* xC    = (unsigned short*)(ws + 524288);  // 1572864 bf16
  unsigned short* Hbuf  = (unsigned short*)(ws + 3670016); // 8192*1536 bf16
  float*          Ybuf  = (float*)(ws + 28835840);         // 8192*768 f32
  unsigned short* fc1T  = (unsigned short*)(ws + 54001664);// [16][1536][768] bf16
  unsigned short* fc2T  = (unsigned short*)(ws + 91750400);// [16][768][1536] bf16

  sniff_kernel<<<1, 64, 0, stream>>>((const unsigned int*)d_in[0], flag);

  conv_kernel<<<2048, 256, 0, stream>>>(
      (const float*)d_in[0], (const float*)d_in[4], (const float*)d_in[5],
      (const float*)d_in[6], (const float*)d_in[8],
      xC, fc1bC, lnwC, lnbC, fc2bC, flag);

  transpose_kernel<768, 1536><<<16 * 12 * 24, 256, 0, stream>>>(
      (const unsigned short*)d_in[3], (const float*)d_in[3], flag, fc1T);
  transpose_kernel<1536, 768><<<16 * 24 * 12, 256, 0, stream>>>(
      (const unsigned short*)d_in[7], (const float*)d_in[7], flag, fc2T);

  gate_kernel<<<T_TOK, 64, 0, stream>>>(
      (const unsigned short*)d_in[0], (const float*)d_in[0],
      (const unsigned short*)d_in[1], (const float*)d_in[1],
      (const unsigned short*)d_in[2], (const float*)d_in[2],
      flag, psel, pw);

  bucket_kernel<<<NE, 256, 0, stream>>>(psel, cnt, plist);

  moe_gemm<D_EMB, H_FFN, true, true, true, false>
      <<<NE * 16 * (H_FFN / 128), 256, 0, stream>>>(
      (const unsigned short*)d_in[0], xC, fc1T,
      (const unsigned short*)d_in[4], fc1bC,
      flag, cnt, plist, Hbuf, nullptr);

  ln_kernel<<<NPAIR, 256, 0, stream>>>(
      Hbuf,
      (const unsigned short*)d_in[5], lnwC,
      (const unsigned short*)d_in[6], lnbC,
      psel, pw, flag);

  moe_gemm<H_FFN, D_EMB, false, false, false, true>
      <<<NE * 16 * (D_EMB / 128), 256, 0, stream>>>(
      Hbuf, Hbuf, fc2T,
      nullptr, nullptr,
      flag, cnt, plist, nullptr, Ybuf);

  combine_kernel<<<T_TOK, 256, 0, stream>>>(
      Ybuf,
      (const unsigned short*)d_in[8], fc2bC,
      psel, pw,
      (unsigned short*)d_out, (float*)d_out, flag);
}

// Round 3
// 390.725 us; speedup vs baseline: 1.0340x; 1.0340x over previous
//
#include <hip/hip_runtime.h>
#include <cmath>

#define T_TOK 2048
#define D_EMB 768
#define H_FFN 1536
#define NE    16
#define NPAIR (T_TOK * 4)

typedef __attribute__((ext_vector_type(8))) short          short8;
typedef __attribute__((ext_vector_type(8))) unsigned short ushort8;
typedef __attribute__((ext_vector_type(4))) unsigned short ushort4v;
typedef __attribute__((ext_vector_type(4))) float          floatx4;

__device__ __forceinline__ float bf2f(unsigned short u) {
  union { unsigned int i; float f; } v; v.i = ((unsigned int)u) << 16; return v.f;
}
__device__ __forceinline__ unsigned short f2bf(float f) {
  union { float f; unsigned int i; } v; v.f = f;
  unsigned int r = v.i + 0x7fffu + ((v.i >> 16) & 1u);   // RNE
  return (unsigned short)(r >> 16);
}

// async global->LDS, 16B per lane. LDS dest is wave-uniform base + lane*16.
__device__ __forceinline__ void gload16(const unsigned short* g, unsigned short* l) {
  __builtin_amdgcn_global_load_lds(
      (const __attribute__((address_space(1))) unsigned int*)g,
      (__attribute__((address_space(3))) unsigned int*)l,
      16, 0, 0);
}

// ---------------- K0: dtype sniff (1 = inputs are bf16) ---------------------
__global__ __launch_bounds__(64) void sniff_kernel(
    const unsigned int* __restrict__ x, int* __restrict__ flag)
{
  int lane = threadIdx.x;
  int c = 0;
  for (int i = 0; i < 8; i++) {
    unsigned int w = x[i * 64 + lane];
    unsigned int e = (w >> 7) & 0xFFu;
    c += (e >= 100u && e <= 140u) ? 1 : 0;
  }
  for (int off = 32; off > 0; off >>= 1) c += __shfl_down(c, off);
  if (lane == 0) *flag = (c > 300) ? 1 : 0;
}

// ---------------- K0b: f32 -> bf16 for x + small vectors (f32 mode only) ----
__global__ __launch_bounds__(256) void conv_kernel(
    const float* __restrict__ x, const float* __restrict__ fc1b,
    const float* __restrict__ lnw, const float* __restrict__ lnb,
    const float* __restrict__ fc2b,
    unsigned short* __restrict__ dx, unsigned short* __restrict__ dfc1b,
    unsigned short* __restrict__ dlnw, unsigned short* __restrict__ dlnb,
    unsigned short* __restrict__ dfc2b, const int* __restrict__ flag)
{
  if (*flag) return;
  int g = blockIdx.x * 256 + threadIdx.x;          // grid 2048*256 = 524288
#pragma unroll
  for (int i = 0; i < 3; i++) dx[g + i * 524288] = f2bf(x[g + i * 524288]);
  if (g < 24576) { dfc1b[g] = f2bf(fc1b[g]); dlnw[g] = f2bf(lnw[g]); dlnb[g] = f2bf(lnb[g]); }
  if (g < 12288) dfc2b[g] = f2bf(fc2b[g]);
}

// ---------------- K0c: weight transpose [e][R][C] -> [e][C][R] bf16 ---------
template<int R, int C>
__global__ __launch_bounds__(256) void transpose_kernel(
    const unsigned short* __restrict__ srcB, const float* __restrict__ srcF,
    const int* __restrict__ flag, unsigned short* __restrict__ dst)
{
  __shared__ __align__(16) unsigned short tile[64][72];
  constexpr int RT = R / 64, CT = C / 64;
  int bx  = blockIdx.x;
  int e   = bx / (RT * CT);
  int rem = bx % (RT * CT);
  int rt  = rem / CT, ct = rem % CT;
  int tid = threadIdx.x;
  int r   = tid >> 2;
  int c   = (tid & 3) * 16;
  int xr  = (r & 7) * 8;                       // XOR swizzle per row
  size_t sbase = ((size_t)e * R + rt * 64 + r) * C + ct * 64 + c;
  if (*flag) {
    ushort8 v0 = *(const ushort8*)(srcB + sbase);
    ushort8 v1 = *(const ushort8*)(srcB + sbase + 8);
    *(ushort8*)&tile[r][(c) ^ xr]     = v0;
    *(ushort8*)&tile[r][(c + 8) ^ xr] = v1;
  } else {
    unsigned short tmp[16];
#pragma unroll
    for (int q = 0; q < 4; q++) {
      floatx4 f = *(const floatx4*)(srcF + sbase + q * 4);
#pragma unroll
      for (int j = 0; j < 4; j++) tmp[q * 4 + j] = f2bf(f[j]);
    }
    *(ushort8*)&tile[r][(c) ^ xr]     = *(ushort8*)&tmp[0];
    *(ushort8*)&tile[r][(c + 8) ^ xr] = *(ushort8*)&tmp[8];
  }
  __syncthreads();
  int n  = tid >> 2;
  int k  = (tid & 3) * 16;
  unsigned short outv[16];
#pragma unroll
  for (int j = 0; j < 16; j++) {
    int kr = k + j;
    outv[j] = tile[kr][n ^ ((kr & 7) * 8)];
  }
  size_t dbase = ((size_t)e * C + ct * 64 + n) * R + rt * 64 + k;
  *(ushort8*)(dst + dbase)     = *(ushort8*)&outv[0];
  *(ushort8*)(dst + dbase + 8) = *(ushort8*)&outv[8];
}

// ---------------- K1: gating, wave-parallel, ZERO atomics -------------------
__global__ __launch_bounds__(64) void gate_kernel(
    const unsigned short* __restrict__ x16, const float* __restrict__ x32,
    const unsigned short* __restrict__ gw16, const float* __restrict__ gw32,
    const unsigned short* __restrict__ gb16, const float* __restrict__ gb32,
    const int* __restrict__ flag,
    int* __restrict__ psel, float* __restrict__ pw)
{
  int t = blockIdx.x;
  int lane = threadIdx.x;
  int isbf = *flag;
  float acc[NE];
#pragma unroll
  for (int e = 0; e < NE; e++) acc[e] = 0.f;
  if (isbf) {
#pragma unroll
    for (int i = 0; i < D_EMB / 64; i++) {
      int d = i * 64 + lane;
      float xv = bf2f(x16[(size_t)t * D_EMB + d]);
      ushort8 g0 = *(const ushort8*)(gw16 + d * NE);
      ushort8 g1 = *(const ushort8*)(gw16 + d * NE + 8);
#pragma unroll
      for (int e = 0; e < 8; e++) acc[e]     += xv * bf2f(g0[e]);
#pragma unroll
      for (int e = 0; e < 8; e++) acc[8 + e] += xv * bf2f(g1[e]);
    }
  } else {
#pragma unroll
    for (int i = 0; i < D_EMB / 64; i++) {
      int d = i * 64 + lane;
      float xv = x32[(size_t)t * D_EMB + d];
#pragma unroll
      for (int q = 0; q < 4; q++) {
        floatx4 g = *(const floatx4*)(gw32 + d * NE + q * 4);
#pragma unroll
        for (int j = 0; j < 4; j++) acc[q * 4 + j] += xv * g[j];
      }
    }
  }
  __shared__ __align__(16) float sacc[64][NE + 1];
#pragma unroll
  for (int e = 0; e < NE; e++) sacc[lane][e] = acc[e];
  __syncthreads();
  int e = lane & 15, q = lane >> 4;
  float s = 0.f;
#pragma unroll
  for (int i = 0; i < 16; i++) s += sacc[q * 16 + i][e];
  s += __shfl_xor(s, 16);
  s += __shfl_xor(s, 32);
  float sv = s + (isbf ? bf2f(gb16[e]) : gb32[e]);
  if (e == 0) sv = -1e9f;
  float m = sv;
#pragma unroll
  for (int off = 8; off > 0; off >>= 1) m = fmaxf(m, __shfl_xor(m, off));
  float pe = expf(sv - m);
  float den = pe;
#pragma unroll
  for (int off = 8; off > 0; off >>= 1) den += __shfl_xor(den, off);
  float pr = pe / den;
  float val = (e == 0) ? -1.f : pr;
  int sel0, sel1, sel2; float sw0, sw1, sw2;
#pragma unroll
  for (int k = 0; k < 3; k++) {
    float bv = val; int bi = e;
#pragma unroll
    for (int off = 8; off > 0; off >>= 1) {
      float ov = __shfl_xor(bv, off);
      int   oi = __shfl_xor(bi, off);
      if (ov > bv || (ov == bv && oi < bi)) { bv = ov; bi = oi; }
    }
    if (k == 0) { sel0 = bi; sw0 = bv; }
    else if (k == 1) { sel1 = bi; sw1 = bv; }
    else { sel2 = bi; sw2 = bv; }
    if (e == bi) val = -1.f;
  }
  if (lane == 0) {
    psel[t * 4] = 0;    pw[t * 4] = 1.0f;
    psel[t * 4 + 1] = sel0; pw[t * 4 + 1] = sw0;
    psel[t * 4 + 2] = sel1; pw[t * 4 + 2] = sw1;
    psel[t * 4 + 3] = sel2; pw[t * 4 + 3] = sw2;
  }
}

// ---------------- K1b: deterministic per-expert compaction (no atomics) -----
__global__ __launch_bounds__(256) void bucket_kernel(
    const int* __restrict__ psel, int* __restrict__ cnt, int* __restrict__ plist)
{
  int e = blockIdx.x;
  int tid = threadIdx.x;
  int wave = tid >> 6, lane = tid & 63;
  __shared__ int wsum[4];
  __shared__ int base;
  if (tid == 0) base = 0;
  __syncthreads();
  for (int c0 = 0; c0 < NPAIR; c0 += 256) {
    bool mt = (psel[c0 + tid] == e);
    unsigned long long mask = __ballot(mt);
    int wcount = __popcll(mask);
    if (lane == 0) wsum[wave] = wcount;
    __syncthreads();
    int wpre = 0;
#pragma unroll
    for (int w = 0; w < 4; w++) if (w < wave) wpre += wsum[w];
    int total = wsum[0] + wsum[1] + wsum[2] + wsum[3];
    if (mt) {
      int off = __popcll(mask & ((1ULL << lane) - 1ULL));
      plist[e * T_TOK + base + wpre + off] = c0 + tid;
    }
    __syncthreads();
    if (tid == 0) base += total;
    __syncthreads();
  }
  if (tid == 0) cnt[e] = base;
}

// ---------------- K2/K4: grouped GEMM, dbuf + counted-vmcnt pipeline --------
// Block tile 128x128, BK=64. 4 waves as 2x2 -> wave tile 64x64.
// Staging via global_load_lds (16B/lane, gathered source, linear LDS dest),
// XOR chunk swizzle on BOTH source address and ds_read side.
// T4 pipeline: issue tile t+1's 8 loads, then s_waitcnt vmcnt(8) (waits ONLY
// for tile t's loads; t+1's stay in flight across the barrier and the whole
// compute phase), raw s_barrier, compute, raw s_barrier (protects buf from
// next iteration's stage). NEVER vmcnt(0) in the main loop.
template<int KDIM, int NDIM, bool GELU, bool HASBIAS, bool AROWDIV4, bool OUTF32>
__global__ __launch_bounds__(256) void moe_gemm(
    const unsigned short* __restrict__ AO, const unsigned short* __restrict__ AC,
    const unsigned short* __restrict__ BT,       // [e][NDIM][KDIM]
    const unsigned short* __restrict__ biasO, const unsigned short* __restrict__ biasC,
    const int* __restrict__ flag,
    const int* __restrict__ cnt, const int* __restrict__ plist,
    unsigned short* __restrict__ outB, float* __restrict__ outF)
{
  const int NSP = NDIM / 128;
  int bx  = blockIdx.x;
  int e   = bx / (16 * NSP);
  int rem = bx % (16 * NSP);
  int mt  = rem / NSP;
  int ns  = rem % NSP;
  int count = cnt[e];
  if (mt * 128 >= count) return;
  const unsigned short* Abase   = (*flag) ? AO : AC;
  const unsigned short* biasAll = (*flag) ? biasO : biasC;

  // Double-buffered linear tiles (required by global_load_lds), 16 KB each.
  __shared__ __align__(16) unsigned short sA[2][128 * 64];
  __shared__ __align__(16) unsigned short sB[2][128 * 64];
  __shared__ int sp[128];

  int tid = threadIdx.x;
  if (tid < 128) {
    int rg  = mt * 128 + tid;
    int idx = rg < count ? rg : count - 1;    // duplicate last row (pad)
    sp[tid] = plist[e * T_TOK + idx];
  }
  __syncthreads();

  int lane = tid & 63;
  int wave = tid >> 6;
  int n0   = ns * 128;

  // --- staging addresses: wave w stages A rows [w*32,w*32+32) and B rows ---
  // ditto, as 4 chunks of 8 rows each. Within a chunk, lane i covers
  // row base+(i>>3), LDS 16B-slot (i&7); source k-chunk = (i&7)^(i>>3).
  int lrow  = lane >> 3;                       // 0..7
  int lsch  = (lane & 7) ^ lrow;               // swizzled source chunk
  const unsigned short* ag[4];
  const unsigned short* bg[4];
  int loff[4];
#pragma unroll
  for (int s = 0; s < 4; s++) {
    int r  = wave * 32 + s * 8;                // chunk base row (local)
    int p  = sp[r + lrow];
    ag[s] = Abase + (size_t)(AROWDIV4 ? (p >> 2) : p) * KDIM + lsch * 8;
    bg[s] = BT + ((size_t)e * NDIM + n0 + r + lrow) * KDIM + lsch * 8;
    loff[s] = r * 64;                          // wave-uniform LDS base (shorts)
  }

  int m16  = lane & 15;
  int quad = lane >> 4;
  int wm   = (wave >> 1) * 64;
  int wn   = (wave & 1) * 64;
  int rsw  = (m16 & 7);                        // read-side XOR (row&7)

  floatx4 acc[4][4];
#pragma unroll
  for (int i = 0; i < 4; i++)
#pragma unroll
    for (int j = 0; j < 4; j++) acc[i][j] = (floatx4){0.f, 0.f, 0.f, 0.f};

  const int NT = KDIM / 64;
  // prologue: stage tile 0 into buffer 0 (8 loads in flight)
#pragma unroll
  for (int s = 0; s < 4; s++) gload16(ag[s], &sA[0][loff[s]]);
#pragma unroll
  for (int s = 0; s < 4; s++) gload16(bg[s], &sB[0][loff[s]]);

  int cur = 0;
#pragma unroll 1
  for (int t = 0; t < NT; ++t) {
    if (t + 1 < NT) {                          // issue next tile's loads NOW
      int k1 = (t + 1) * 64;
#pragma unroll
      for (int s = 0; s < 4; s++) gload16(ag[s] + k1, &sA[cur ^ 1][loff[s]]);
#pragma unroll
      for (int s = 0; s < 4; s++) gload16(bg[s] + k1, &sB[cur ^ 1][loff[s]]);
      // wait for tile t's 8 loads only; tile t+1's 8 remain in flight
      asm volatile("s_waitcnt vmcnt(8)" ::: "memory");
    } else {
      asm volatile("s_waitcnt vmcnt(0)" ::: "memory");
    }
    __builtin_amdgcn_sched_barrier(0);
    __builtin_amdgcn_s_barrier();              // all waves' stages landed
    __builtin_amdgcn_sched_barrier(0);
#pragma unroll
    for (int ks = 0; ks < 2; ks++) {
      int ch = ((ks * 4 + quad) ^ rsw) * 8;    // swizzled k-chunk (shorts)
      short8 af[4], bf[4];
#pragma unroll
      for (int m = 0; m < 4; m++)
        af[m] = *(const short8*)(&sA[cur][0] + (wm + m * 16 + m16) * 64 + ch);
#pragma unroll
      for (int n = 0; n < 4; n++)
        bf[n] = *(const short8*)(&sB[cur][0] + (wn + n * 16 + m16) * 64 + ch);
#pragma unroll
      for (int m = 0; m < 4; m++)
#pragma unroll
        for (int n = 0; n < 4; n++)
          acc[m][n] = __builtin_amdgcn_mfma_f32_16x16x32_bf16(af[m], bf[n], acc[m][n], 0, 0, 0);
    }
    __builtin_amdgcn_sched_barrier(0);
    __builtin_amdgcn_s_barrier();              // reads done before next stage
    __builtin_amdgcn_sched_barrier(0);
    cur ^= 1;
  }

  // epilogue: C/D col = lane&15 (-> n dim), row = quad*4 + reg (-> m dim)
#pragma unroll
  for (int m = 0; m < 4; m++) {
#pragma unroll
    for (int r = 0; r < 4; r++) {
      int row_local = wm + m * 16 + quad * 4 + r;
      int rg = mt * 128 + row_local;
      if (rg < count) {
        int p = sp[row_local];
#pragma unroll
        for (int n = 0; n < 4; n++) {
          int col = n0 + wn + n * 16 + m16;
          float v = acc[m][n][r];
          if (HASBIAS) v += bf2f(biasAll[e * NDIM + col]);
          if (GELU)    v = 0.5f * v * (1.f + erff(v * 0.70710678118654752f));
          if (OUTF32) outF[(size_t)p * NDIM + col] = v;
          else        outB[(size_t)p * NDIM + col] = f2bf(v);
        }
      }
    }
  }
}

// ---------------- K3: LayerNorm per pair, combine weight folded in ----------
__global__ __launch_bounds__(256) void ln_kernel(
    unsigned short* __restrict__ Hbuf,
    const unsigned short* __restrict__ lnwO, const unsigned short* __restrict__ lnwC,
    const unsigned short* __restrict__ lnbO, const unsigned short* __restrict__ lnbC,
    const int* __restrict__ psel, const float* __restrict__ pw,
    const int* __restrict__ flag)
{
  int p = blockIdx.x;
  int tid = threadIdx.x;
  int e = psel[p];
  int isbf = *flag;
  const unsigned short* lnw = isbf ? lnwO : lnwC;
  const unsigned short* lnb = isbf ? lnbO : lnbC;
  unsigned short* hr = Hbuf + (size_t)p * H_FFN;
  bool act = tid < 192;
  float v[8];
  float s = 0.f, sq = 0.f;
  if (act) {
    ushort8 hv = *(const ushort8*)(hr + tid * 8);
#pragma unroll
    for (int j = 0; j < 8; j++) { v[j] = bf2f(hv[j]); s += v[j]; sq += v[j] * v[j]; }
  }
#pragma unroll
  for (int off = 32; off > 0; off >>= 1) {
    s  += __shfl_down(s, off);
    sq += __shfl_down(sq, off);
  }
  __shared__ float red[8];
  int wave = tid >> 6, lane = tid & 63;
  if (lane == 0) { red[wave * 2] = s; red[wave * 2 + 1] = sq; }
  __syncthreads();
  __shared__ float mv[2];
  if (tid == 0) {
    float S = 0.f, Q = 0.f;
    for (int w = 0; w < 4; w++) { S += red[w * 2]; Q += red[w * 2 + 1]; }
    float mu  = S * (1.f / H_FFN);
    float var = Q * (1.f / H_FFN) - mu * mu;
    mv[0] = mu; mv[1] = rsqrtf(var + 1e-5f);
  }
  __syncthreads();
  if (act) {
    float mu = mv[0], rstd = mv[1];
    float w = pw[p];
    ushort8 lw = *(const ushort8*)(lnw + e * H_FFN + tid * 8);
    ushort8 lb = *(const ushort8*)(lnb + e * H_FFN + tid * 8);
    ushort8 o;
#pragma unroll
    for (int j = 0; j < 8; j++)
      o[j] = f2bf(((v[j] - mu) * rstd * bf2f(lw[j]) + bf2f(lb[j])) * w);
    *(ushort8*)(hr + tid * 8) = o;
  }
}

// ---------------- K5: sum 4 pair outputs + weighted fc2 bias ----------------
__global__ __launch_bounds__(256) void combine_kernel(
    const float* __restrict__ Y,
    const unsigned short* __restrict__ b2O, const unsigned short* __restrict__ b2C,
    const int* __restrict__ psel, const float* __restrict__ pw,
    unsigned short* __restrict__ out16, float* __restrict__ out32,
    const int* __restrict__ flag)
{
  int t = blockIdx.x;
  int tid = threadIdx.x;
  if (tid >= 192) return;
  int isbf = *flag;
  const unsigned short* b2 = isbf ? b2O : b2C;
  int e1 = psel[t * 4 + 1], e2 = psel[t * 4 + 2], e3 = psel[t * 4 + 3];
  float w1 = pw[t * 4 + 1], w2 = pw[t * 4 + 2], w3 = pw[t * 4 + 3];
  int d = tid * 4;
  const float* Yb = Y + (size_t)t * 4 * D_EMB + d;
  floatx4 y0 = *(const floatx4*)(Yb);
  floatx4 y1 = *(const floatx4*)(Yb + D_EMB);
  floatx4 y2 = *(const floatx4*)(Yb + 2 * D_EMB);
  floatx4 y3 = *(const floatx4*)(Yb + 3 * D_EMB);
  ushort4v b0 = *(const ushort4v*)(b2 + d);
  ushort4v bb1 = *(const ushort4v*)(b2 + e1 * D_EMB + d);
  ushort4v bb2 = *(const ushort4v*)(b2 + e2 * D_EMB + d);
  ushort4v bb3 = *(const ushort4v*)(b2 + e3 * D_EMB + d);
  if (isbf) {
    ushort4v o;
#pragma unroll
    for (int j = 0; j < 4; j++) {
      float a = y0[j] + y1[j] + y2[j] + y3[j] + bf2f(b0[j])
              + w1 * bf2f(bb1[j]) + w2 * bf2f(bb2[j]) + w3 * bf2f(bb3[j]);
      o[j] = f2bf(a);
    }
    *(ushort4v*)(out16 + (size_t)t * D_EMB + d) = o;
  } else {
    floatx4 o;
#pragma unroll
    for (int j = 0; j < 4; j++)
      o[j] = y0[j] + y1[j] + y2[j] + y3[j] + bf2f(b0[j])
           + w1 * bf2f(bb1[j]) + w2 * bf2f(bb2[j]) + w3 * bf2f(bb3[j]);
    *(floatx4*)(out32 + (size_t)t * D_EMB + d) = o;
  }
}

extern "C" void kernel_launch(void* const* d_in, const int* in_sizes, int n_in,
                              void* d_out, int out_size, void* d_ws, size_t ws_size,
                              hipStream_t stream)
{
  (void)in_sizes; (void)n_in; (void)out_size; (void)ws_size;
  char* ws = (char*)d_ws;
  int*   cnt   = (int*)ws;                                 // 16 ints
  int*   plist = (int*)(ws + 256);                         // 16*2048 ints
  int*   psel  = (int*)(ws + 131328);                      // 8192 ints
  float* pw    = (float*)(ws + 164096);                    // 8192 f32
  int*   flag  = (int*)(ws + 196864);
  unsigned short* fc1bC = (unsigned short*)(ws + 197120);  // 24576 bf16
  unsigned short* lnwC  = (unsigned short*)(ws + 246272);
  unsigned short* lnbC  = (unsigned short*)(ws + 295424);
  unsigned short* fc2bC = (unsigned short*)(ws + 344576);  // 12288 bf16
  unsigned short* xC    = (unsigned short*)(ws + 524288);  // 1572864 bf16
  unsigned short* Hbuf  = (unsigned short*)(ws + 3670016); // 8192*1536 bf16
  float*          Ybuf  = (float*)(ws + 28835840);         // 8192*768 f32
  unsigned short* fc1T  = (unsigned short*)(ws + 54001664);// [16][1536][768] bf16
  unsigned short* fc2T  = (unsigned short*)(ws + 91750400);// [16][768][1536] bf16

  sniff_kernel<<<1, 64, 0, stream>>>((const unsigned int*)d_in[0], flag);

  conv_kernel<<<2048, 256, 0, stream>>>(
      (const float*)d_in[0], (const float*)d_in[4], (const float*)d_in[5],
      (const float*)d_in[6], (const float*)d_in[8],
      xC, fc1bC, lnwC, lnbC, fc2bC, flag);

  transpose_kernel<768, 1536><<<16 * 12 * 24, 256, 0, stream>>>(
      (const unsigned short*)d_in[3], (const float*)d_in[3], flag, fc1T);
  transpose_kernel<1536, 768><<<16 * 24 * 12, 256, 0, stream>>>(
      (const unsigned short*)d_in[7], (const float*)d_in[7], flag, fc2T);

  gate_kernel<<<T_TOK, 64, 0, stream>>>(
      (const unsigned short*)d_in[0], (const float*)d_in[0],
      (const unsigned short*)d_in[1], (const float*)d_in[1],
      (const unsigned short*)d_in[2], (const float*)d_in[2],
      flag, psel, pw);

  bucket_kernel<<<NE, 256, 0, stream>>>(psel, cnt, plist);

  moe_gemm<D_EMB, H_FFN, true, true, true, false>
      <<<NE * 16 * (H_FFN / 128), 256, 0, stream>>>(
      (const unsigned short*)d_in[0], xC, fc1T,
      (const unsigned short*)d_in[4], fc1bC,
      flag, cnt, plist, Hbuf, nullptr);

  ln_kernel<<<NPAIR, 256, 0, stream>>>(
      Hbuf,
      (const unsigned short*)d_in[5], lnwC,
      (const unsigned short*)d_in[6], lnbC,
      psel, pw, flag);

  moe_gemm<H_FFN, D_EMB, false, false, false, true>
      <<<NE * 16 * (D_EMB / 128), 256, 0, stream>>>(
      Hbuf, Hbuf, fc2T,
      nullptr, nullptr,
      flag, cnt, plist, nullptr, Ybuf);

  combine_kernel<<<T_TOK, 256, 0, stream>>>(
      Ybuf,
      (const unsigned short*)d_in[8], fc2bC,
      psel, pw,
      (unsigned short*)d_out, (float*)d_out, flag);
}

// Round 4
// 362.132 us; speedup vs baseline: 1.1156x; 1.0790x over previous
//
#include <hip/hip_runtime.h>
#include <cmath>

#define T_TOK 2048
#define D_EMB 768
#define H_FFN 1536
#define NE    16
#define NPAIR (T_TOK * 4)

typedef __attribute__((ext_vector_type(8))) short          short8;
typedef __attribute__((ext_vector_type(8))) unsigned short ushort8;
typedef __attribute__((ext_vector_type(4))) unsigned short ushort4v;
typedef __attribute__((ext_vector_type(4))) float          floatx4;

__device__ __forceinline__ float bf2f(unsigned short u) {
  union { unsigned int i; float f; } v; v.i = ((unsigned int)u) << 16; return v.f;
}
__device__ __forceinline__ unsigned short f2bf(float f) {
  union { float f; unsigned int i; } v; v.f = f;
  unsigned int r = v.i + 0x7fffu + ((v.i >> 16) & 1u);   // RNE
  return (unsigned short)(r >> 16);
}

// async global->LDS, 16B per lane. LDS dest is wave-uniform base + lane*16.
__device__ __forceinline__ void gload16(const unsigned short* g, unsigned short* l) {
  __builtin_amdgcn_global_load_lds(
      (const __attribute__((address_space(1))) unsigned int*)g,
      (__attribute__((address_space(3))) unsigned int*)l,
      16, 0, 0);
}

// ---------------- K0: dtype sniff (1 = inputs are bf16) ---------------------
__global__ __launch_bounds__(64) void sniff_kernel(
    const unsigned int* __restrict__ x, int* __restrict__ flag)
{
  int lane = threadIdx.x;
  int c = 0;
  for (int i = 0; i < 8; i++) {
    unsigned int w = x[i * 64 + lane];
    unsigned int e = (w >> 7) & 0xFFu;
    c += (e >= 100u && e <= 140u) ? 1 : 0;
  }
  for (int off = 32; off > 0; off >>= 1) c += __shfl_down(c, off);
  if (lane == 0) *flag = (c > 300) ? 1 : 0;
}

// ---------------- K0b: f32 -> bf16 for x + small vectors (f32 mode only) ----
__global__ __launch_bounds__(256) void conv_kernel(
    const float* __restrict__ x, const float* __restrict__ fc1b,
    const float* __restrict__ lnw, const float* __restrict__ lnb,
    const float* __restrict__ fc2b,
    unsigned short* __restrict__ dx, unsigned short* __restrict__ dfc1b,
    unsigned short* __restrict__ dlnw, unsigned short* __restrict__ dlnb,
    unsigned short* __restrict__ dfc2b, const int* __restrict__ flag)
{
  if (*flag) return;
  int g = blockIdx.x * 256 + threadIdx.x;          // grid 2048*256 = 524288
#pragma unroll
  for (int i = 0; i < 3; i++) dx[g + i * 524288] = f2bf(x[g + i * 524288]);
  if (g < 24576) { dfc1b[g] = f2bf(fc1b[g]); dlnw[g] = f2bf(lnw[g]); dlnb[g] = f2bf(lnb[g]); }
  if (g < 12288) dfc2b[g] = f2bf(fc2b[g]);
}

// ---------------- K0c: weight transpose [e][R][C] -> [e][C][R] bf16 ---------
template<int R, int C>
__global__ __launch_bounds__(256) void transpose_kernel(
    const unsigned short* __restrict__ srcB, const float* __restrict__ srcF,
    const int* __restrict__ flag, unsigned short* __restrict__ dst)
{
  __shared__ __align__(16) unsigned short tile[64][72];
  constexpr int RT = R / 64, CT = C / 64;
  int bx  = blockIdx.x;
  int e   = bx / (RT * CT);
  int rem = bx % (RT * CT);
  int rt  = rem / CT, ct = rem % CT;
  int tid = threadIdx.x;
  int r   = tid >> 2;
  int c   = (tid & 3) * 16;
  int xr  = (r & 7) * 8;                       // XOR swizzle per row
  size_t sbase = ((size_t)e * R + rt * 64 + r) * C + ct * 64 + c;
  if (*flag) {
    ushort8 v0 = *(const ushort8*)(srcB + sbase);
    ushort8 v1 = *(const ushort8*)(srcB + sbase + 8);
    *(ushort8*)&tile[r][(c) ^ xr]     = v0;
    *(ushort8*)&tile[r][(c + 8) ^ xr] = v1;
  } else {
    unsigned short tmp[16];
#pragma unroll
    for (int q = 0; q < 4; q++) {
      floatx4 f = *(const floatx4*)(srcF + sbase + q * 4);
#pragma unroll
      for (int j = 0; j < 4; j++) tmp[q * 4 + j] = f2bf(f[j]);
    }
    *(ushort8*)&tile[r][(c) ^ xr]     = *(ushort8*)&tmp[0];
    *(ushort8*)&tile[r][(c + 8) ^ xr] = *(ushort8*)&tmp[8];
  }
  __syncthreads();
  int n  = tid >> 2;
  int k  = (tid & 3) * 16;
  unsigned short outv[16];
#pragma unroll
  for (int j = 0; j < 16; j++) {
    int kr = k + j;
    outv[j] = tile[kr][n ^ ((kr & 7) * 8)];
  }
  size_t dbase = ((size_t)e * C + ct * 64 + n) * R + rt * 64 + k;
  *(ushort8*)(dst + dbase)     = *(ushort8*)&outv[0];
  *(ushort8*)(dst + dbase + 8) = *(ushort8*)&outv[8];
}

// ---------------- K1: gating, wave-parallel, ZERO atomics -------------------
__global__ __launch_bounds__(64) void gate_kernel(
    const unsigned short* __restrict__ x16, const float* __restrict__ x32,
    const unsigned short* __restrict__ gw16, const float* __restrict__ gw32,
    const unsigned short* __restrict__ gb16, const float* __restrict__ gb32,
    const int* __restrict__ flag,
    int* __restrict__ psel, float* __restrict__ pw)
{
  int t = blockIdx.x;
  int lane = threadIdx.x;
  int isbf = *flag;
  float acc[NE];
#pragma unroll
  for (int e = 0; e < NE; e++) acc[e] = 0.f;
  if (isbf) {
#pragma unroll
    for (int i = 0; i < D_EMB / 64; i++) {
      int d = i * 64 + lane;
      float xv = bf2f(x16[(size_t)t * D_EMB + d]);
      ushort8 g0 = *(const ushort8*)(gw16 + d * NE);
      ushort8 g1 = *(const ushort8*)(gw16 + d * NE + 8);
#pragma unroll
      for (int e = 0; e < 8; e++) acc[e]     += xv * bf2f(g0[e]);
#pragma unroll
      for (int e = 0; e < 8; e++) acc[8 + e] += xv * bf2f(g1[e]);
    }
  } else {
#pragma unroll
    for (int i = 0; i < D_EMB / 64; i++) {
      int d = i * 64 + lane;
      float xv = x32[(size_t)t * D_EMB + d];
#pragma unroll
      for (int q = 0; q < 4; q++) {
        floatx4 g = *(const floatx4*)(gw32 + d * NE + q * 4);
#pragma unroll
        for (int j = 0; j < 4; j++) acc[q * 4 + j] += xv * g[j];
      }
    }
  }
  __shared__ __align__(16) float sacc[64][NE + 1];
#pragma unroll
  for (int e = 0; e < NE; e++) sacc[lane][e] = acc[e];
  __syncthreads();
  int e = lane & 15, q = lane >> 4;
  float s = 0.f;
#pragma unroll
  for (int i = 0; i < 16; i++) s += sacc[q * 16 + i][e];
  s += __shfl_xor(s, 16);
  s += __shfl_xor(s, 32);
  float sv = s + (isbf ? bf2f(gb16[e]) : gb32[e]);
  if (e == 0) sv = -1e9f;
  float m = sv;
#pragma unroll
  for (int off = 8; off > 0; off >>= 1) m = fmaxf(m, __shfl_xor(m, off));
  float pe = expf(sv - m);
  float den = pe;
#pragma unroll
  for (int off = 8; off > 0; off >>= 1) den += __shfl_xor(den, off);
  float pr = pe / den;
  float val = (e == 0) ? -1.f : pr;
  int sel0, sel1, sel2; float sw0, sw1, sw2;
#pragma unroll
  for (int k = 0; k < 3; k++) {
    float bv = val; int bi = e;
#pragma unroll
    for (int off = 8; off > 0; off >>= 1) {
      float ov = __shfl_xor(bv, off);
      int   oi = __shfl_xor(bi, off);
      if (ov > bv || (ov == bv && oi < bi)) { bv = ov; bi = oi; }
    }
    if (k == 0) { sel0 = bi; sw0 = bv; }
    else if (k == 1) { sel1 = bi; sw1 = bv; }
    else { sel2 = bi; sw2 = bv; }
    if (e == bi) val = -1.f;
  }
  if (lane == 0) {
    psel[t * 4] = 0;    pw[t * 4] = 1.0f;
    psel[t * 4 + 1] = sel0; pw[t * 4 + 1] = sw0;
    psel[t * 4 + 2] = sel1; pw[t * 4 + 2] = sw1;
    psel[t * 4 + 3] = sel2; pw[t * 4 + 3] = sw2;
  }
}

// ---------------- K1b: deterministic per-expert compaction (no atomics) -----
__global__ __launch_bounds__(256) void bucket_kernel(
    const int* __restrict__ psel, int* __restrict__ cnt, int* __restrict__ plist)
{
  int e = blockIdx.x;
  int tid = threadIdx.x;
  int wave = tid >> 6, lane = tid & 63;
  __shared__ int wsum[4];
  __shared__ int base;
  if (tid == 0) base = 0;
  __syncthreads();
  for (int c0 = 0; c0 < NPAIR; c0 += 256) {
    bool mt = (psel[c0 + tid] == e);
    unsigned long long mask = __ballot(mt);
    int wcount = __popcll(mask);
    if (lane == 0) wsum[wave] = wcount;
    __syncthreads();
    int wpre = 0;
#pragma unroll
    for (int w = 0; w < 4; w++) if (w < wave) wpre += wsum[w];
    int total = wsum[0] + wsum[1] + wsum[2] + wsum[3];
    if (mt) {
      int off = __popcll(mask & ((1ULL << lane) - 1ULL));
      plist[e * T_TOK + base + wpre + off] = c0 + tid;
    }
    __syncthreads();
    if (tid == 0) base += total;
    __syncthreads();
  }
  if (tid == 0) cnt[e] = base;
}

// ---------------- K2/K4: grouped GEMM, 64x128 tile, occupancy-first ---------
// Block tile 64x128, BK=64, single LDS buffer (24.8 KB -> 6 blocks/CU).
// 4 waves as 2x2 -> wave tile 32x64. Latency hiding comes from cross-block
// TLP (6 resident blocks interleave through each other's vmcnt drains),
// which R0/R1 measurements showed beats intra-block dbuf pipelining here.
// Staging via global_load_lds (16B/lane, gathered source, linear LDS dest),
// XOR chunk swizzle on BOTH source address and ds_read side (2-way = free).
template<int KDIM, int NDIM, bool GELU, bool HASBIAS, bool AROWDIV4, bool OUTF32>
__global__ __launch_bounds__(256, 6) void moe_gemm(
    const unsigned short* __restrict__ AO, const unsigned short* __restrict__ AC,
    const unsigned short* __restrict__ BT,       // [e][NDIM][KDIM]
    const unsigned short* __restrict__ biasO, const unsigned short* __restrict__ biasC,
    const int* __restrict__ flag,
    const int* __restrict__ cnt, const int* __restrict__ plist,
    unsigned short* __restrict__ outB, float* __restrict__ outF)
{
  const int NSP = NDIM / 128;
  int bx  = blockIdx.x;
  int e   = bx / (32 * NSP);
  int rem = bx % (32 * NSP);
  int mt  = rem / NSP;
  int ns  = rem % NSP;
  int count = cnt[e];
  if (mt * 64 >= count) return;
  const unsigned short* Abase   = (*flag) ? AO : AC;
  const unsigned short* biasAll = (*flag) ? biasO : biasC;

  // Single-buffer linear tiles (required by global_load_lds).
  __shared__ __align__(16) unsigned short sA[64 * 64];    // 8 KB
  __shared__ __align__(16) unsigned short sB[128 * 64];   // 16 KB
  __shared__ int sp[64];

  int tid = threadIdx.x;
  if (tid < 64) {
    int rg  = mt * 64 + tid;
    int idx = rg < count ? rg : count - 1;    // duplicate last row (pad)
    sp[tid] = plist[e * T_TOK + idx];
  }
  __syncthreads();

  int lane = tid & 63;
  int wave = tid >> 6;
  int n0   = ns * 128;

  // --- staging: wave w stages A rows [w*16,w*16+16) (2 chunks of 8) and ---
  // B rows [w*32,w*32+32) (4 chunks of 8). Within a chunk, lane i covers
  // row base+(i>>3), LDS 16B-slot (i&7); source k-chunk = (i&7)^(i>>3).
  int lrow  = lane >> 3;                       // 0..7
  int lsch  = (lane & 7) ^ lrow;               // swizzled source chunk
  const unsigned short* ag[2];
  const unsigned short* bg[4];
  int laoff[2], lboff[4];
#pragma unroll
  for (int s = 0; s < 2; s++) {
    int r  = wave * 16 + s * 8;                // A chunk base row (local)
    int p  = sp[r + lrow];
    ag[s] = Abase + (size_t)(AROWDIV4 ? (p >> 2) : p) * KDIM + lsch * 8;
    laoff[s] = r * 64;
  }
#pragma unroll
  for (int s = 0; s < 4; s++) {
    int r  = wave * 32 + s * 8;                // B chunk base row (local)
    bg[s] = BT + ((size_t)e * NDIM + n0 + r + lrow) * KDIM + lsch * 8;
    lboff[s] = r * 64;
  }

  int m16  = lane & 15;
  int quad = lane >> 4;
  int wm   = (wave >> 1) * 32;
  int wn   = (wave & 1) * 64;
  int rsw  = (m16 & 7);                        // read-side XOR (row&7)

  floatx4 acc[2][4];
#pragma unroll
  for (int i = 0; i < 2; i++)
#pragma unroll
    for (int j = 0; j < 4; j++) acc[i][j] = (floatx4){0.f, 0.f, 0.f, 0.f};

  for (int k0 = 0; k0 < KDIM; k0 += 64) {
    if (k0) __syncthreads();                   // prev iter's LDS reads done
#pragma unroll
    for (int s = 0; s < 2; s++) gload16(ag[s] + k0, sA + laoff[s]);
#pragma unroll
    for (int s = 0; s < 4; s++) gload16(bg[s] + k0, sB + lboff[s]);
    __syncthreads();                           // vmcnt(0) drain: tile landed
#pragma unroll
    for (int ks = 0; ks < 2; ks++) {
      int ch = ((ks * 4 + quad) ^ rsw) * 8;    // swizzled k-chunk (shorts)
      short8 af[2], bf[4];
#pragma unroll
      for (int m = 0; m < 2; m++)
        af[m] = *(const short8*)(sA + (wm + m * 16 + m16) * 64 + ch);
#pragma unroll
      for (int n = 0; n < 4; n++)
        bf[n] = *(const short8*)(sB + (wn + n * 16 + m16) * 64 + ch);
#pragma unroll
      for (int m = 0; m < 2; m++)
#pragma unroll
        for (int n = 0; n < 4; n++)
          acc[m][n] = __builtin_amdgcn_mfma_f32_16x16x32_bf16(af[m], bf[n], acc[m][n], 0, 0, 0);
    }
  }

  // epilogue: C/D col = lane&15 (-> n dim), row = quad*4 + reg (-> m dim)
#pragma unroll
  for (int m = 0; m < 2; m++) {
#pragma unroll
    for (int r = 0; r < 4; r++) {
      int row_local = wm + m * 16 + quad * 4 + r;
      int rg = mt * 64 + row_local;
      if (rg < count) {
        int p = sp[row_local];
#pragma unroll
        for (int n = 0; n < 4; n++) {
          int col = n0 + wn + n * 16 + m16;
          float v = acc[m][n][r];
          if (HASBIAS) v += bf2f(biasAll[e * NDIM + col]);
          if (GELU)    v = 0.5f * v * (1.f + erff(v * 0.70710678118654752f));
          if (OUTF32) outF[(size_t)p * NDIM + col] = v;
          else        outB[(size_t)p * NDIM + col] = f2bf(v);
        }
      }
    }
  }
}

// ---------------- K3: LayerNorm per pair, combine weight folded in ----------
__global__ __launch_bounds__(256) void ln_kernel(
    unsigned short* __restrict__ Hbuf,
    const unsigned short* __restrict__ lnwO, const unsigned short* __restrict__ lnwC,
    const unsigned short* __restrict__ lnbO, const unsigned short* __restrict__ lnbC,
    const int* __restrict__ psel, const float* __restrict__ pw,
    const int* __restrict__ flag)
{
  int p = blockIdx.x;
  int tid = threadIdx.x;
  int e = psel[p];
  int isbf = *flag;
  const unsigned short* lnw = isbf ? lnwO : lnwC;
  const unsigned short* lnb = isbf ? lnbO : lnbC;
  unsigned short* hr = Hbuf + (size_t)p * H_FFN;
  bool act = tid < 192;
  float v[8];
  float s = 0.f, sq = 0.f;
  if (act) {
    ushort8 hv = *(const ushort8*)(hr + tid * 8);
#pragma unroll
    for (int j = 0; j < 8; j++) { v[j] = bf2f(hv[j]); s += v[j]; sq += v[j] * v[j]; }
  }
#pragma unroll
  for (int off = 32; off > 0; off >>= 1) {
    s  += __shfl_down(s, off);
    sq += __shfl_down(sq, off);
  }
  __shared__ float red[8];
  int wave = tid >> 6, lane = tid & 63;
  if (lane == 0) { red[wave * 2] = s; red[wave * 2 + 1] = sq; }
  __syncthreads();
  __shared__ float mv[2];
  if (tid == 0) {
    float S = 0.f, Q = 0.f;
    for (int w = 0; w < 4; w++) { S += red[w * 2]; Q += red[w * 2 + 1]; }
    float mu  = S * (1.f / H_FFN);
    float var = Q * (1.f / H_FFN) - mu * mu;
    mv[0] = mu; mv[1] = rsqrtf(var + 1e-5f);
  }
  __syncthreads();
  if (act) {
    float mu = mv[0], rstd = mv[1];
    float w = pw[p];
    ushort8 lw = *(const ushort8*)(lnw + e * H_FFN + tid * 8);
    ushort8 lb = *(const ushort8*)(lnb + e * H_FFN + tid * 8);
    ushort8 o;
#pragma unroll
    for (int j = 0; j < 8; j++)
      o[j] = f2bf(((v[j] - mu) * rstd * bf2f(lw[j]) + bf2f(lb[j])) * w);
    *(ushort8*)(hr + tid * 8) = o;
  }
}

// ---------------- K5: sum 4 pair outputs + weighted fc2 bias ----------------
__global__ __launch_bounds__(256) void combine_kernel(
    const float* __restrict__ Y,
    const unsigned short* __restrict__ b2O, const unsigned short* __restrict__ b2C,
    const int* __restrict__ psel, const float* __restrict__ pw,
    unsigned short* __restrict__ out16, float* __restrict__ out32,
    const int* __restrict__ flag)
{
  int t = blockIdx.x;
  int tid = threadIdx.x;
  if (tid >= 192) return;
  int isbf = *flag;
  const unsigned short* b2 = isbf ? b2O : b2C;
  int e1 = psel[t * 4 + 1], e2 = psel[t * 4 + 2], e3 = psel[t * 4 + 3];
  float w1 = pw[t * 4 + 1], w2 = pw[t * 4 + 2], w3 = pw[t * 4 + 3];
  int d = tid * 4;
  const float* Yb = Y + (size_t)t * 4 * D_EMB + d;
  floatx4 y0 = *(const floatx4*)(Yb);
  floatx4 y1 = *(const floatx4*)(Yb + D_EMB);
  floatx4 y2 = *(const floatx4*)(Yb + 2 * D_EMB);
  floatx4 y3 = *(const floatx4*)(Yb + 3 * D_EMB);
  ushort4v b0 = *(const ushort4v*)(b2 + d);
  ushort4v bb1 = *(const ushort4v*)(b2 + e1 * D_EMB + d);
  ushort4v bb2 = *(const ushort4v*)(b2 + e2 * D_EMB + d);
  ushort4v bb3 = *(const ushort4v*)(b2 + e3 * D_EMB + d);
  if (isbf) {
    ushort4v o;
#pragma unroll
    for (int j = 0; j < 4; j++) {
      float a = y0[j] + y1[j] + y2[j] + y3[j] + bf2f(b0[j])
              + w1 * bf2f(bb1[j]) + w2 * bf2f(bb2[j]) + w3 * bf2f(bb3[j]);
      o[j] = f2bf(a);
    }
    *(ushort4v*)(out16 + (size_t)t * D_EMB + d) = o;
  } else {
    floatx4 o;
#pragma unroll
    for (int j = 0; j < 4; j++)
      o[j] = y0[j] + y1[j] + y2[j] + y3[j] + bf2f(b0[j])
           + w1 * bf2f(bb1[j]) + w2 * bf2f(bb2[j]) + w3 * bf2f(bb3[j]);
    *(floatx4*)(out32 + (size_t)t * D_EMB + d) = o;
  }
}

extern "C" void kernel_launch(void* const* d_in, const int* in_sizes, int n_in,
                              void* d_out, int out_size, void* d_ws, size_t ws_size,
                              hipStream_t stream)
{
  (void)in_sizes; (void)n_in; (void)out_size; (void)ws_size;
  char* ws = (char*)d_ws;
  int*   cnt   = (int*)ws;                                 // 16 ints
  int*   plist = (int*)(ws + 256);                         // 16*2048 ints
  int*   psel  = (int*)(ws + 131328);                      // 8192 ints
  float* pw    = (float*)(ws + 164096);                    // 8192 f32
  int*   flag  = (int*)(ws + 196864);
  unsigned short* fc1bC = (unsigned short*)(ws + 197120);  // 24576 bf16
  unsigned short* lnwC  = (unsigned short*)(ws + 246272);
  unsigned short* lnbC  = (unsigned short*)(ws + 295424);
  unsigned short* fc2bC = (unsigned short*)(ws + 344576);  // 12288 bf16
  unsigned short* xC    = (unsigned short*)(ws + 524288);  // 1572864 bf16
  unsigned short* Hbuf  = (unsigned short*)(ws + 3670016); // 8192*1536 bf16
  float*          Ybuf  = (float*)(ws + 28835840);         // 8192*768 f32
  unsigned short* fc1T  = (unsigned short*)(ws + 54001664);// [16][1536][768] bf16
  unsigned short* fc2T  = (unsigned short*)(ws + 91750400);// [16][768][1536] bf16

  sniff_kernel<<<1, 64, 0, stream>>>((const unsigned int*)d_in[0], flag);

  conv_kernel<<<2048, 256, 0, stream>>>(
      (const float*)d_in[0], (const float*)d_in[4], (const float*)d_in[5],
      (const float*)d_in[6], (const float*)d_in[8],
      xC, fc1bC, lnwC, lnbC, fc2bC, flag);

  transpose_kernel<768, 1536><<<16 * 12 * 24, 256, 0, stream>>>(
      (const unsigned short*)d_in[3], (const float*)d_in[3], flag, fc1T);
  transpose_kernel<1536, 768><<<16 * 24 * 12, 256, 0, stream>>>(
      (const unsigned short*)d_in[7], (const float*)d_in[7], flag, fc2T);

  gate_kernel<<<T_TOK, 64, 0, stream>>>(
      (const unsigned short*)d_in[0], (const float*)d_in[0],
      (const unsigned short*)d_in[1], (const float*)d_in[1],
      (const unsigned short*)d_in[2], (const float*)d_in[2],
      flag, psel, pw);

  bucket_kernel<<<NE, 256, 0, stream>>>(psel, cnt, plist);

  moe_gemm<D_EMB, H_FFN, true, true, true, false>
      <<<NE * 32 * (H_FFN / 128), 256, 0, stream>>>(
      (const unsigned short*)d_in[0], xC, fc1T,
      (const unsigned short*)d_in[4], fc1bC,
      flag, cnt, plist, Hbuf, nullptr);

  ln_kernel<<<NPAIR, 256, 0, stream>>>(
      Hbuf,
      (const unsigned short*)d_in[5], lnwC,
      (const unsigned short*)d_in[6], lnbC,
      psel, pw, flag);

  moe_gemm<H_FFN, D_EMB, false, false, false, true>
      <<<NE * 32 * (D_EMB / 128), 256, 0, stream>>>(
      Hbuf, Hbuf, fc2T,
      nullptr, nullptr,
      flag, cnt, plist, nullptr, Ybuf);

  combine_kernel<<<T_TOK, 256, 0, stream>>>(
      Ybuf,
      (const unsigned short*)d_in[8], fc2bC,
      psel, pw,
      (unsigned short*)d_out, (float*)d_out, flag);
}

// Round 5
// 354.236 us; speedup vs baseline: 1.1405x; 1.0223x over previous
//
#include <hip/hip_runtime.h>
#include <cmath>

#define T_TOK 2048
#define D_EMB 768
#define H_FFN 1536
#define NE    16
#define NPAIR (T_TOK * 4)

// prep_kernel block-range partition
#define NT1   4608                 // fc1_w transpose: 16 * 12 * 24
#define NT2   4608                 // fc2_w transpose: 16 * 24 * 12
#define NCONV 2048                 // x/bias f32->bf16 conversion
#define NGATE 512                  // gating: 4 tokens per block

typedef __attribute__((ext_vector_type(8))) short          short8;
typedef __attribute__((ext_vector_type(8))) unsigned short ushort8;
typedef __attribute__((ext_vector_type(4))) unsigned short ushort4v;
typedef __attribute__((ext_vector_type(4))) float          floatx4;

__device__ __forceinline__ float bf2f(unsigned short u) {
  union { unsigned int i; float f; } v; v.i = ((unsigned int)u) << 16; return v.f;
}
__device__ __forceinline__ unsigned short f2bf(float f) {
  union { float f; unsigned int i; } v; v.f = f;
  unsigned int r = v.i + 0x7fffu + ((v.i >> 16) & 1u);   // RNE
  return (unsigned short)(r >> 16);
}

// async global->LDS, 16B per lane. LDS dest is wave-uniform base + lane*16.
__device__ __forceinline__ void gload16(const unsigned short* g, unsigned short* l) {
  __builtin_amdgcn_global_load_lds(
      (const __attribute__((address_space(1))) unsigned int*)g,
      (__attribute__((address_space(3))) unsigned int*)l,
      16, 0, 0);
}

// per-block dtype sniff: 256 threads x 2 words = same 512 words / threshold
// as the old sniff_kernel; deterministic and identical across blocks.
__device__ __forceinline__ int block_sniff(const unsigned int* __restrict__ xw, int tid) {
  int c = 0;
#pragma unroll
  for (int i = 0; i < 2; i++) {
    unsigned int w = xw[tid * 2 + i];
    unsigned int e = (w >> 7) & 0xFFu;
    c += (e >= 100u && e <= 140u) ? 1 : 0;
  }
#pragma unroll
  for (int off = 32; off > 0; off >>= 1) c += __shfl_down(c, off);
  __shared__ int ssn[4];
  int wave = tid >> 6, lane = tid & 63;
  if (lane == 0) ssn[wave] = c;
  __syncthreads();
  return (ssn[0] + ssn[1] + ssn[2] + ssn[3] > 300) ? 1 : 0;
}

// weight transpose [e][R][C] -> [e][C][R] bf16, one 64x64 tile per block
template<int R, int C>
__device__ __forceinline__ void transpose_body(
    const unsigned short* __restrict__ srcB, const float* __restrict__ srcF,
    int isbf, unsigned short* __restrict__ dst, int bx, int tid,
    unsigned char* smemraw)
{
  auto tile = (unsigned short(*)[72])smemraw;
  constexpr int RT = R / 64, CT = C / 64;
  int e   = bx / (RT * CT);
  int rem = bx % (RT * CT);
  int rt  = rem / CT, ct = rem % CT;
  int r   = tid >> 2;
  int c   = (tid & 3) * 16;
  int xr  = (r & 7) * 8;                       // XOR swizzle per row
  size_t sbase = ((size_t)e * R + rt * 64 + r) * C + ct * 64 + c;
  if (isbf) {
    ushort8 v0 = *(const ushort8*)(srcB + sbase);
    ushort8 v1 = *(const ushort8*)(srcB + sbase + 8);
    *(ushort8*)&tile[r][(c) ^ xr]     = v0;
    *(ushort8*)&tile[r][(c + 8) ^ xr] = v1;
  } else {
    unsigned short tmp[16];
#pragma unroll
    for (int q = 0; q < 4; q++) {
      floatx4 f = *(const floatx4*)(srcF + sbase + q * 4);
#pragma unroll
      for (int j = 0; j < 4; j++) tmp[q * 4 + j] = f2bf(f[j]);
    }
    *(ushort8*)&tile[r][(c) ^ xr]     = *(ushort8*)&tmp[0];
    *(ushort8*)&tile[r][(c + 8) ^ xr] = *(ushort8*)&tmp[8];
  }
  __syncthreads();
  int n  = tid >> 2;
  int k  = (tid & 3) * 16;
  unsigned short outv[16];
#pragma unroll
  for (int j = 0; j < 16; j++) {
    int kr = k + j;
    outv[j] = tile[kr][n ^ ((kr & 7) * 8)];
  }
  size_t dbase = ((size_t)e * C + ct * 64 + n) * R + rt * 64 + k;
  *(ushort8*)(dst + dbase)     = *(ushort8*)&outv[0];
  *(ushort8*)(dst + dbase + 8) = *(ushort8*)&outv[8];
}

// ---------------- K_PREP: fused sniff + transposes + conv + gate + bucket ---
// All preprocessing is mutually independent -> one launch, segments by bid.
// Gate builds plist directly via atomicAdd(cnt[e]) — list order is
// nondeterministic but per-row GEMM results are bitwise identical regardless
// of tile grouping, so outputs are unchanged. cnt zeroed by hipMemsetAsync.
__global__ __launch_bounds__(256) void prep_kernel(
    const unsigned int* __restrict__ xw,
    const unsigned short* __restrict__ x16, const float* __restrict__ x32,
    const unsigned short* __restrict__ gw16, const float* __restrict__ gw32,
    const unsigned short* __restrict__ gb16, const float* __restrict__ gb32,
    const unsigned short* __restrict__ w1B, const float* __restrict__ w1F,
    const unsigned short* __restrict__ w2B, const float* __restrict__ w2F,
    const float* __restrict__ fc1bF, const float* __restrict__ lnwF,
    const float* __restrict__ lnbF, const float* __restrict__ fc2bF,
    unsigned short* __restrict__ xC,
    unsigned short* __restrict__ dfc1b, unsigned short* __restrict__ dlnw,
    unsigned short* __restrict__ dlnb, unsigned short* __restrict__ dfc2b,
    unsigned short* __restrict__ fc1T, unsigned short* __restrict__ fc2T,
    int* __restrict__ flagOut,
    int* __restrict__ psel, float* __restrict__ pw,
    int* __restrict__ cnt, int* __restrict__ plist)
{
  __shared__ __align__(16) unsigned char smem[4 * 64 * 17 * 4];  // 17408 B
  int bid = blockIdx.x;
  int tid = threadIdx.x;
  int isbf = block_sniff(xw, tid);
  if (bid == 0 && tid == 0) *flagOut = isbf;

  if (bid < NT1) {
    transpose_body<768, 1536>(w1B, w1F, isbf, fc1T, bid, tid, smem);
  } else if (bid < NT1 + NT2) {
    transpose_body<1536, 768>(w2B, w2F, isbf, fc2T, bid - NT1, tid, smem);
  } else if (bid < NT1 + NT2 + NCONV) {
    if (!isbf) {
      int g = (bid - NT1 - NT2) * 256 + tid;   // 2048*256 = 524288
#pragma unroll
      for (int i = 0; i < 3; i++) xC[g + i * 524288] = f2bf(x32[g + i * 524288]);
      if (g < 24576) { dfc1b[g] = f2bf(fc1bF[g]); dlnw[g] = f2bf(lnwF[g]); dlnb[g] = f2bf(lnbF[g]); }
      if (g < 12288) dfc2b[g] = f2bf(fc2bF[g]);
    }
  } else {
    // ---- gate: 4 waves, one token each ----
    int wave = tid >> 6, lane = tid & 63;
    int t = (bid - (NT1 + NT2 + NCONV)) * 4 + wave;
    float acc[NE];
#pragma unroll
    for (int e = 0; e < NE; e++) acc[e] = 0.f;
    if (isbf) {
#pragma unroll
      for (int i = 0; i < D_EMB / 64; i++) {
        int d = i * 64 + lane;
        float xv = bf2f(x16[(size_t)t * D_EMB + d]);
        ushort8 g0 = *(const ushort8*)(gw16 + d * NE);
        ushort8 g1 = *(const ushort8*)(gw16 + d * NE + 8);
#pragma unroll
        for (int e = 0; e < 8; e++) acc[e]     += xv * bf2f(g0[e]);
#pragma unroll
        for (int e = 0; e < 8; e++) acc[8 + e] += xv * bf2f(g1[e]);
      }
    } else {
#pragma unroll
      for (int i = 0; i < D_EMB / 64; i++) {
        int d = i * 64 + lane;
        float xv = x32[(size_t)t * D_EMB + d];
#pragma unroll
        for (int q = 0; q < 4; q++) {
          floatx4 g = *(const floatx4*)(gw32 + d * NE + q * 4);
#pragma unroll
          for (int j = 0; j < 4; j++) acc[q * 4 + j] += xv * g[j];
        }
      }
    }
    auto sacc = (float(*)[64][17])smem;
#pragma unroll
    for (int e = 0; e < NE; e++) sacc[wave][lane][e] = acc[e];
    __syncthreads();
    int e = lane & 15, q = lane >> 4;
    float s = 0.f;
#pragma unroll
    for (int i = 0; i < 16; i++) s += sacc[wave][q * 16 + i][e];
    s += __shfl_xor(s, 16);
    s += __shfl_xor(s, 32);
    float sv = s + (isbf ? bf2f(gb16[e]) : gb32[e]);
    if (e == 0) sv = -1e9f;
    float m = sv;
#pragma unroll
    for (int off = 8; off > 0; off >>= 1) m = fmaxf(m, __shfl_xor(m, off));
    float pe = expf(sv - m);
    float den = pe;
#pragma unroll
    for (int off = 8; off > 0; off >>= 1) den += __shfl_xor(den, off);
    float pr = pe / den;
    float val = (e == 0) ? -1.f : pr;
    int sel0, sel1, sel2; float sw0, sw1, sw2;
#pragma unroll
    for (int k = 0; k < 3; k++) {
      float bv = val; int bi = e;
#pragma unroll
      for (int off = 8; off > 0; off >>= 1) {
        float ov = __shfl_xor(bv, off);
        int   oi = __shfl_xor(bi, off);
        if (ov > bv || (ov == bv && oi < bi)) { bv = ov; bi = oi; }
      }
      if (k == 0) { sel0 = bi; sw0 = bv; }
      else if (k == 1) { sel1 = bi; sw1 = bv; }
      else { sel2 = bi; sw2 = bv; }
      if (e == bi) val = -1.f;
    }
    if (lane < 4) {
      int se; float swt;
      if (lane == 0)      { se = 0;    swt = 1.0f; }
      else if (lane == 1) { se = sel0; swt = sw0; }
      else if (lane == 2) { se = sel1; swt = sw1; }
      else                { se = sel2; swt = sw2; }
      int pidx = t * 4 + lane;
      psel[pidx] = se; pw[pidx] = swt;
      int pos = atomicAdd(&cnt[se], 1);
      plist[se * T_TOK + pos] = pidx;
    }
  }
}

// ---------------- K2/K4: grouped GEMM (R1 structure: best measured) ---------
// Block tile 128x128, BK=64, single LDS buffer. 4 waves as 2x2 -> 64x64.
// Staging via global_load_lds (16B/lane, gathered source, linear LDS dest),
// XOR chunk swizzle on BOTH source address and ds_read side (2-way = free).
template<int KDIM, int NDIM, bool GELU, bool HASBIAS, bool AROWDIV4, bool OUTF32>
__global__ __launch_bounds__(256) void moe_gemm(
    const unsigned short* __restrict__ AO, const unsigned short* __restrict__ AC,
    const unsigned short* __restrict__ BT,       // [e][NDIM][KDIM]
    const unsigned short* __restrict__ biasO, const unsigned short* __restrict__ biasC,
    const int* __restrict__ flag,
    const int* __restrict__ cnt, const int* __restrict__ plist,
    unsigned short* __restrict__ outB, float* __restrict__ outF)
{
  const int NSP = NDIM / 128;
  int bx  = blockIdx.x;
  int e   = bx / (16 * NSP);
  int rem = bx % (16 * NSP);
  int mt  = rem / NSP;
  int ns  = rem % NSP;
  int count = cnt[e];
  if (mt * 128 >= count) return;
  const unsigned short* Abase   = (*flag) ? AO : AC;
  const unsigned short* biasAll = (*flag) ? biasO : biasC;

  __shared__ __align__(16) unsigned short sA[128 * 64];
  __shared__ __align__(16) unsigned short sB[128 * 64];
  __shared__ int sp[128];

  int tid = threadIdx.x;
  if (tid < 128) {
    int rg  = mt * 128 + tid;
    int idx = rg < count ? rg : count - 1;    // duplicate last row (pad)
    sp[tid] = plist[e * T_TOK + idx];
  }
  __syncthreads();

  int lane = tid & 63;
  int wave = tid >> 6;
  int n0   = ns * 128;

  int lrow  = lane >> 3;                       // 0..7
  int lsch  = (lane & 7) ^ lrow;               // swizzled source chunk
  const unsigned short* ag[4];
  const unsigned short* bg[4];
  int loff[4];
#pragma unroll
  for (int s = 0; s < 4; s++) {
    int r  = wave * 32 + s * 8;                // chunk base row (local)
    int p  = sp[r + lrow];
    ag[s] = Abase + (size_t)(AROWDIV4 ? (p >> 2) : p) * KDIM + lsch * 8;
    bg[s] = BT + ((size_t)e * NDIM + n0 + r + lrow) * KDIM + lsch * 8;
    loff[s] = r * 64;                          // wave-uniform LDS base (shorts)
  }

  int m16  = lane & 15;
  int quad = lane >> 4;
  int wm   = (wave >> 1) * 64;
  int wn   = (wave & 1) * 64;
  int rsw  = (m16 & 7);                        // read-side XOR (row&7)

  floatx4 acc[4][4];
#pragma unroll
  for (int i = 0; i < 4; i++)
#pragma unroll
    for (int j = 0; j < 4; j++) acc[i][j] = (floatx4){0.f, 0.f, 0.f, 0.f};

  for (int k0 = 0; k0 < KDIM; k0 += 64) {
    if (k0) __syncthreads();                   // prev iter's LDS reads done
#pragma unroll
    for (int s = 0; s < 4; s++) gload16(ag[s] + k0, sA + loff[s]);
#pragma unroll
    for (int s = 0; s < 4; s++) gload16(bg[s] + k0, sB + loff[s]);
    __syncthreads();                           // vmcnt(0) drain: tile landed
#pragma unroll
    for (int ks = 0; ks < 2; ks++) {
      int ch = ((ks * 4 + quad) ^ rsw) * 8;    // swizzled k-chunk (shorts)
      short8 af[4], bf[4];
#pragma unroll
      for (int m = 0; m < 4; m++)
        af[m] = *(const short8*)(sA + (wm + m * 16 + m16) * 64 + ch);
#pragma unroll
      for (int n = 0; n < 4; n++)
        bf[n] = *(const short8*)(sB + (wn + n * 16 + m16) * 64 + ch);
#pragma unroll
      for (int m = 0; m < 4; m++)
#pragma unroll
        for (int n = 0; n < 4; n++)
          acc[m][n] = __builtin_amdgcn_mfma_f32_16x16x32_bf16(af[m], bf[n], acc[m][n], 0, 0, 0);
    }
  }

  // epilogue: C/D col = lane&15 (-> n dim), row = quad*4 + reg (-> m dim)
#pragma unroll
  for (int m = 0; m < 4; m++) {
#pragma unroll
    for (int r = 0; r < 4; r++) {
      int row_local = wm + m * 16 + quad * 4 + r;
      int rg = mt * 128 + row_local;
      if (rg < count) {
        int p = sp[row_local];
#pragma unroll
        for (int n = 0; n < 4; n++) {
          int col = n0 + wn + n * 16 + m16;
          float v = acc[m][n][r];
          if (HASBIAS) v += bf2f(biasAll[e * NDIM + col]);
          if (GELU)    v = 0.5f * v * (1.f + erff(v * 0.70710678118654752f));
          if (OUTF32) outF[(size_t)p * NDIM + col] = v;
          else        outB[(size_t)p * NDIM + col] = f2bf(v);
        }
      }
    }
  }
}

// ---------------- K3: LayerNorm per pair, combine weight folded in ----------
__global__ __launch_bounds__(256) void ln_kernel(
    unsigned short* __restrict__ Hbuf,
    const unsigned short* __restrict__ lnwO, const unsigned short* __restrict__ lnwC,
    const unsigned short* __restrict__ lnbO, const unsigned short* __restrict__ lnbC,
    const int* __restrict__ psel, const float* __restrict__ pw,
    const int* __restrict__ flag)
{
  int p = blockIdx.x;
  int tid = threadIdx.x;
  int e = psel[p];
  int isbf = *flag;
  const unsigned short* lnw = isbf ? lnwO : lnwC;
  const unsigned short* lnb = isbf ? lnbO : lnbC;
  unsigned short* hr = Hbuf + (size_t)p * H_FFN;
  bool act = tid < 192;
  float v[8];
  float s = 0.f, sq = 0.f;
  if (act) {
    ushort8 hv = *(const ushort8*)(hr + tid * 8);
#pragma unroll
    for (int j = 0; j < 8; j++) { v[j] = bf2f(hv[j]); s += v[j]; sq += v[j] * v[j]; }
  }
#pragma unroll
  for (int off = 32; off > 0; off >>= 1) {
    s  += __shfl_down(s, off);
    sq += __shfl_down(sq, off);
  }
  __shared__ float red[8];
  int wave = tid >> 6, lane = tid & 63;
  if (lane == 0) { red[wave * 2] = s; red[wave * 2 + 1] = sq; }
  __syncthreads();
  __shared__ float mv[2];
  if (tid == 0) {
    float S = 0.f, Q = 0.f;
    for (int w = 0; w < 4; w++) { S += red[w * 2]; Q += red[w * 2 + 1]; }
    float mu  = S * (1.f / H_FFN);
    float var = Q * (1.f / H_FFN) - mu * mu;
    mv[0] = mu; mv[1] = rsqrtf(var + 1e-5f);
  }
  __syncthreads();
  if (act) {
    float mu = mv[0], rstd = mv[1];
    float w = pw[p];
    ushort8 lw = *(const ushort8*)(lnw + e * H_FFN + tid * 8);
    ushort8 lb = *(const ushort8*)(lnb + e * H_FFN + tid * 8);
    ushort8 o;
#pragma unroll
    for (int j = 0; j < 8; j++)
      o[j] = f2bf(((v[j] - mu) * rstd * bf2f(lw[j]) + bf2f(lb[j])) * w);
    *(ushort8*)(hr + tid * 8) = o;
  }
}

// ---------------- K5: sum 4 pair outputs + weighted fc2 bias ----------------
__global__ __launch_bounds__(192) void combine_kernel(
    const float* __restrict__ Y,
    const unsigned short* __restrict__ b2O, const unsigned short* __restrict__ b2C,
    const int* __restrict__ psel, const float* __restrict__ pw,
    unsigned short* __restrict__ out16, float* __restrict__ out32,
    const int* __restrict__ flag)
{
  int t = blockIdx.x;
  int tid = threadIdx.x;                       // 192 threads, 192*4 = 768
  int isbf = *flag;
  const unsigned short* b2 = isbf ? b2O : b2C;
  int e1 = psel[t * 4 + 1], e2 = psel[t * 4 + 2], e3 = psel[t * 4 + 3];
  float w1 = pw[t * 4 + 1], w2 = pw[t * 4 + 2], w3 = pw[t * 4 + 3];
  int d = tid * 4;
  const float* Yb = Y + (size_t)t * 4 * D_EMB + d;
  floatx4 y0 = *(const floatx4*)(Yb);
  floatx4 y1 = *(const floatx4*)(Yb + D_EMB);
  floatx4 y2 = *(const floatx4*)(Yb + 2 * D_EMB);
  floatx4 y3 = *(const floatx4*)(Yb + 3 * D_EMB);
  ushort4v b0 = *(const ushort4v*)(b2 + d);
  ushort4v bb1 = *(const ushort4v*)(b2 + e1 * D_EMB + d);
  ushort4v bb2 = *(const ushort4v*)(b2 + e2 * D_EMB + d);
  ushort4v bb3 = *(const ushort4v*)(b2 + e3 * D_EMB + d);
  if (isbf) {
    ushort4v o;
#pragma unroll
    for (int j = 0; j < 4; j++) {
      float a = y0[j] + y1[j] + y2[j] + y3[j] + bf2f(b0[j])
              + w1 * bf2f(bb1[j]) + w2 * bf2f(bb2[j]) + w3 * bf2f(bb3[j]);
      o[j] = f2bf(a);
    }
    *(ushort4v*)(out16 + (size_t)t * D_EMB + d) = o;
  } else {
    floatx4 o;
#pragma unroll
    for (int j = 0; j < 4; j++)
      o[j] = y0[j] + y1[j] + y2[j] + y3[j] + bf2f(b0[j])
           + w1 * bf2f(bb1[j]) + w2 * bf2f(bb2[j]) + w3 * bf2f(bb3[j]);
    *(floatx4*)(out32 + (size_t)t * D_EMB + d) = o;
  }
}

extern "C" void kernel_launch(void* const* d_in, const int* in_sizes, int n_in,
                              void* d_out, int out_size, void* d_ws, size_t ws_size,
                              hipStream_t stream)
{
  (void)in_sizes; (void)n_in; (void)out_size; (void)ws_size;
  char* ws = (char*)d_ws;
  int*   cnt   = (int*)ws;                                 // 16 ints
  int*   plist = (int*)(ws + 256);                         // 16*2048 ints
  int*   psel  = (int*)(ws + 131328);                      // 8192 ints
  float* pw    = (float*)(ws + 164096);                    // 8192 f32
  int*   flag  = (int*)(ws + 196864);
  unsigned short* fc1bC = (unsigned short*)(ws + 197120);  // 24576 bf16
  unsigned short* lnwC  = (unsigned short*)(ws + 246272);
  unsigned short* lnbC  = (unsigned short*)(ws + 295424);
  unsigned short* fc2bC = (unsigned short*)(ws + 344576);  // 12288 bf16
  unsigned short* xC    = (unsigned short*)(ws + 524288);  // 1572864 bf16
  unsigned short* Hbuf  = (unsigned short*)(ws + 3670016); // 8192*1536 bf16
  float*          Ybuf  = (float*)(ws + 28835840);         // 8192*768 f32
  unsigned short* fc1T  = (unsigned short*)(ws + 54001664);// [16][1536][768] bf16
  unsigned short* fc2T  = (unsigned short*)(ws + 91750400);// [16][768][1536] bf16

  hipMemsetAsync(cnt, 0, 64, stream);                      // zero expert counters

  prep_kernel<<<NT1 + NT2 + NCONV + NGATE, 256, 0, stream>>>(
      (const unsigned int*)d_in[0],
      (const unsigned short*)d_in[0], (const float*)d_in[0],
      (const unsigned short*)d_in[1], (const float*)d_in[1],
      (const unsigned short*)d_in[2], (const float*)d_in[2],
      (const unsigned short*)d_in[3], (const float*)d_in[3],
      (const unsigned short*)d_in[7], (const float*)d_in[7],
      (const float*)d_in[4], (const float*)d_in[5],
      (const float*)d_in[6], (const float*)d_in[8],
      xC, fc1bC, lnwC, lnbC, fc2bC,
      fc1T, fc2T,
      flag, psel, pw, cnt, plist);

  moe_gemm<D_EMB, H_FFN, true, true, true, false>
      <<<NE * 16 * (H_FFN / 128), 256, 0, stream>>>(
      (const unsigned short*)d_in[0], xC, fc1T,
      (const unsigned short*)d_in[4], fc1bC,
      flag, cnt, plist, Hbuf, nullptr);

  ln_kernel<<<NPAIR, 256, 0, stream>>>(
      Hbuf,
      (const unsigned short*)d_in[5], lnwC,
      (const unsigned short*)d_in[6], lnbC,
      psel, pw, flag);

  moe_gemm<H_FFN, D_EMB, false, false, false, true>
      <<<NE * 16 * (D_EMB / 128), 256, 0, stream>>>(
      Hbuf, Hbuf, fc2T,
      nullptr, nullptr,
      flag, cnt, plist, nullptr, Ybuf);

  combine_kernel<<<T_TOK, 192, 0, stream>>>(
      Ybuf,
      (const unsigned short*)d_in[8], fc2bC,
      psel, pw,
      (unsigned short*)d_out, (float*)d_out, flag);
}

// Round 8
// 350.754 us; speedup vs baseline: 1.1518x; 1.0099x over previous
//
#include <hip/hip_runtime.h>
#include <cmath>

#define T_TOK 2048
#define D_EMB 768
#define H_FFN 1536
#define NE    16
#define NPAIR (T_TOK * 4)

// prep_kernel block-range partition (segments are independent)
#define NW1   9216                 // fc1_w f32->bf16: 9216*256*8 = 18,874,368
#define NW2   9216                 // fc2_w f32->bf16
#define NX    768                  // x f32->bf16: 768*256*8 = 1,572,864
#define NB    12                   // biases: 12*256*8 = 24576
#define NGATE 512                  // gating: 4 tokens per block

typedef __attribute__((ext_vector_type(8))) short          short8;
typedef __attribute__((ext_vector_type(4))) short          short4v;
typedef __attribute__((ext_vector_type(8))) unsigned short ushort8;
typedef __attribute__((ext_vector_type(4))) unsigned short ushort4v;
typedef __attribute__((ext_vector_type(4))) float          floatx4;

__device__ __forceinline__ float bf2f(unsigned short u) {
  union { unsigned int i; float f; } v; v.i = ((unsigned int)u) << 16; return v.f;
}
__device__ __forceinline__ unsigned short f2bf(float f) {
  union { float f; unsigned int i; } v; v.f = f;
  unsigned int r = v.i + 0x7fffu + ((v.i >> 16) & 1u);   // RNE
  return (unsigned short)(r >> 16);
}

// async global->LDS, 16B per lane. LDS dest is wave-uniform base + lane*16.
__device__ __forceinline__ void gload16(const unsigned short* g, unsigned short* l) {
  __builtin_amdgcn_global_load_lds(
      (const __attribute__((address_space(1))) unsigned int*)g,
      (__attribute__((address_space(3))) unsigned int*)l,
      16, 0, 0);
}

// 32-bit LDS byte offset of a __shared__ pointer
__device__ __forceinline__ unsigned ldsaddr(const void* p) {
  return (unsigned)(unsigned long long)
      (const __attribute__((address_space(3))) char*)p;
}

// hardware transpose read (cross-lane within each 16-lane group):
// each lane fetches 8B at its own vaddr; the group's 128B (a 4x16 bf16
// row-major tile when vaddr = tile_base + (l&15)*8) is redistributed so
// lane l's 4 elems = column (l&15): tile[j*16 + (l&15)], j=0..3.
__device__ __forceinline__ short4v tr8(unsigned a) {
  short4v d;
  asm volatile("ds_read_b64_tr_b16 %0, %1" : "=v"(d) : "v"(a));
  return d;
}

// per-block dtype sniff: 256 threads x 2 words; deterministic across blocks.
__device__ __forceinline__ int block_sniff(const unsigned int* __restrict__ xw, int tid) {
  int c = 0;
#pragma unroll
  for (int i = 0; i < 2; i++) {
    unsigned int w = xw[tid * 2 + i];
    unsigned int e = (w >> 7) & 0xFFu;
    c += (e >= 100u && e <= 140u) ? 1 : 0;
  }
#pragma unroll
  for (int off = 32; off > 0; off >>= 1) c += __shfl_down(c, off);
  __shared__ int ssn[4];
  int wave = tid >> 6, lane = tid & 63;
  if (lane == 0) ssn[wave] = c;
  __syncthreads();
  return (ssn[0] + ssn[1] + ssn[2] + ssn[3] > 300) ? 1 : 0;
}

__device__ __forceinline__ void conv8(const float* __restrict__ src,
                                      unsigned short* __restrict__ dst, size_t i) {
  floatx4 a = *(const floatx4*)(src + i);
  floatx4 b = *(const floatx4*)(src + i + 4);
  ushort8 o;
#pragma unroll
  for (int j = 0; j < 4; j++) { o[j] = f2bf(a[j]); o[4 + j] = f2bf(b[j]); }
  *(ushort8*)(dst + i) = o;
}

// ---------------- K_PREP: fused sniff + convert(W1,W2,x,biases) + gate ------
// No transposes: GEMM consumes native-layout weights via tr-reads.
// All conversion segments are pure streaming (no LDS, no barriers); in bf16
// mode they are no-ops and prep reduces to the gate segment.
__global__ __launch_bounds__(256) void prep_kernel(
    const unsigned int* __restrict__ xw,
    const unsigned short* __restrict__ x16, const float* __restrict__ x32,
    const unsigned short* __restrict__ gw16, const float* __restrict__ gw32,
    const unsigned short* __restrict__ gb16, const float* __restrict__ gb32,
    const float* __restrict__ w1F, const float* __restrict__ w2F,
    const float* __restrict__ fc1bF, const float* __restrict__ lnwF,
    const float* __restrict__ lnbF, const float* __restrict__ fc2bF,
    unsigned short* __restrict__ xC,
    unsigned short* __restrict__ wsW1, unsigned short* __restrict__ wsW2,
    unsigned short* __restrict__ dfc1b, unsigned short* __restrict__ dlnw,
    unsigned short* __restrict__ dlnb, unsigned short* __restrict__ dfc2b,
    int* __restrict__ flagOut,
    int* __restrict__ psel, float* __restrict__ pw,
    int* __restrict__ cnt, int* __restrict__ plist)
{
  __shared__ __align__(16) float sacc[4][64][17];
  int bid = blockIdx.x;
  int tid = threadIdx.x;
  int isbf = block_sniff(xw, tid);
  if (bid == 0 && tid == 0) *flagOut = isbf;

  if (bid < NW1) {
    if (!isbf) conv8(w1F, wsW1, ((size_t)bid * 256 + tid) * 8);
  } else if (bid < NW1 + NW2) {
    if (!isbf) conv8(w2F, wsW2, ((size_t)(bid - NW1) * 256 + tid) * 8);
  } else if (bid < NW1 + NW2 + NX) {
    if (!isbf) conv8(x32, xC, ((size_t)(bid - NW1 - NW2) * 256 + tid) * 8);
  } else if (bid < NW1 + NW2 + NX + NB) {
    if (!isbf) {
      size_t g = (size_t)(bid - NW1 - NW2 - NX) * 256 + tid;   // [0, 3072)
      size_t i = g * 8;
      conv8(fc1bF, dfc1b, i);
      conv8(lnwF,  dlnw,  i);
      conv8(lnbF,  dlnb,  i);
      if (g < 1536) conv8(fc2bF, dfc2b, i);
    }
  } else {
    // ---- gate: 4 waves, one token each ----
    int wave = tid >> 6, lane = tid & 63;
    int t = (bid - (NW1 + NW2 + NX + NB)) * 4 + wave;
    float acc[NE];
#pragma unroll
    for (int e = 0; e < NE; e++) acc[e] = 0.f;
    if (isbf) {
#pragma unroll
      for (int i = 0; i < D_EMB / 64; i++) {
        int d = i * 64 + lane;
        float xv = bf2f(x16[(size_t)t * D_EMB + d]);
        ushort8 g0 = *(const ushort8*)(gw16 + d * NE);
        ushort8 g1 = *(const ushort8*)(gw16 + d * NE + 8);
#pragma unroll
        for (int e = 0; e < 8; e++) acc[e]     += xv * bf2f(g0[e]);
#pragma unroll
        for (int e = 0; e < 8; e++) acc[8 + e] += xv * bf2f(g1[e]);
      }
    } else {
#pragma unroll
      for (int i = 0; i < D_EMB / 64; i++) {
        int d = i * 64 + lane;
        float xv = x32[(size_t)t * D_EMB + d];
#pragma unroll
        for (int q = 0; q < 4; q++) {
          floatx4 g = *(const floatx4*)(gw32 + d * NE + q * 4);
#pragma unroll
          for (int j = 0; j < 4; j++) acc[q * 4 + j] += xv * g[j];
        }
      }
    }
#pragma unroll
    for (int e = 0; e < NE; e++) sacc[wave][lane][e] = acc[e];
    __syncthreads();
    int e = lane & 15, q = lane >> 4;
    float s = 0.f;
#pragma unroll
    for (int i = 0; i < 16; i++) s += sacc[wave][q * 16 + i][e];
    s += __shfl_xor(s, 16);
    s += __shfl_xor(s, 32);
    float sv = s + (isbf ? bf2f(gb16[e]) : gb32[e]);
    if (e == 0) sv = -1e9f;
    float m = sv;
#pragma unroll
    for (int off = 8; off > 0; off >>= 1) m = fmaxf(m, __shfl_xor(m, off));
    float pe = expf(sv - m);
    float den = pe;
#pragma unroll
    for (int off = 8; off > 0; off >>= 1) den += __shfl_xor(den, off);
    float pr = pe / den;
    float val = (e == 0) ? -1.f : pr;
    int sel0, sel1, sel2; float sw0, sw1, sw2;
#pragma unroll
    for (int k = 0; k < 3; k++) {
      float bv = val; int bi = e;
#pragma unroll
      for (int off = 8; off > 0; off >>= 1) {
        float ov = __shfl_xor(bv, off);
        int   oi = __shfl_xor(bi, off);
        if (ov > bv || (ov == bv && oi < bi)) { bv = ov; bi = oi; }
      }
      if (k == 0) { sel0 = bi; sw0 = bv; }
      else if (k == 1) { sel1 = bi; sw1 = bv; }
      else { sel2 = bi; sw2 = bv; }
      if (e == bi) val = -1.f;
    }
    if (lane < 4) {
      int se; float swt;
      if (lane == 0)      { se = 0;    swt = 1.0f; }
      else if (lane == 1) { se = sel0; swt = sw0; }
      else if (lane == 2) { se = sel1; swt = sw1; }
      else                { se = sel2; swt = sw2; }
      int pidx = t * 4 + lane;
      psel[pidx] = se; pw[pidx] = swt;
      int pos = atomicAdd(&cnt[se], 1);
      plist[se * T_TOK + pos] = pidx;
    }
  }
}

// ---------------- K2/K4: grouped GEMM, NATIVE-layout B via tr-reads ---------
// Block tile 128x128, BK=64, single LDS buffer. 4 waves as 2x2 -> 64x64.
// A: gathered rows, k-contiguous, XOR-swizzled source+read (as R1).
// B: native [e][KDIM][NDIM]. Staged subtiled: elem (k,n) of the 64x128 tile at
//   LDS idx (k>>2)*512 + (n>>4)*64 + (k&3)*16 + (n&15). Achieved with linear
//   LDS dest + permuted per-lane GLOBAL source: issue s of wave w covers
//   kb=w*4+s; lane l's 16B = B[k=4kb+((l>>1)&3)][n0+(l>>3)*16+(l&1)*8 ..+8].
// B-fragment elem j = B[ks*32+quad*8+j][wn+nt*16+m16] via 2x ds_read_b64_tr_b16.
//   tr semantics (m156): group of 16 lanes each fetch 8B at own vaddr; with
//   vaddr = tile_base + (l&15)*8 the 4x16 row-major tile is delivered
//   column-wise: lane l elem j = tile[j*16 + (l&15)].
//   tile_base(bytes) = ks*8192 + quad*2048 + (wave&1)*512 + nt*128
//   per-lane vaddr  = sB + tile_base + m16*8 ; second half (j=4..7) at +1024.
template<int KDIM, int NDIM, bool GELU, bool HASBIAS, bool AROWDIV4, bool OUTF32>
__global__ __launch_bounds__(256) void moe_gemm(
    const unsigned short* __restrict__ AO, const unsigned short* __restrict__ AC,
    const unsigned short* __restrict__ BO, const unsigned short* __restrict__ BC,
    const unsigned short* __restrict__ biasO, const unsigned short* __restrict__ biasC,
    const int* __restrict__ flag,
    const int* __restrict__ cnt, const int* __restrict__ plist,
    unsigned short* __restrict__ outB, float* __restrict__ outF)
{
  const int NSP = NDIM / 128;
  int bx  = blockIdx.x;
  int e   = bx / (16 * NSP);
  int rem = bx % (16 * NSP);
  int mt  = rem / NSP;
  int ns  = rem % NSP;
  int count = cnt[e];
  if (mt * 128 >= count) return;
  const unsigned short* Abase   = (*flag) ? AO : AC;
  const unsigned short* Bbase   = (*flag) ? BO : BC;
  const unsigned short* biasAll = (*flag) ? biasO : biasC;

  __shared__ __align__(16) unsigned short sA[128 * 64];
  __shared__ __align__(16) unsigned short sB[64 * 128];   // subtiled
  __shared__ int sp[128];

  int tid = threadIdx.x;
  if (tid < 128) {
    int rg  = mt * 128 + tid;
    int idx = rg < count ? rg : count - 1;    // duplicate last row (pad)
    sp[tid] = plist[e * T_TOK + idx];
  }
  __syncthreads();

  int lane = tid & 63;
  int wave = tid >> 6;
  int n0   = ns * 128;

  // --- A staging (XOR chunk swizzle on source + read, as R1) ---
  int lrow  = lane >> 3;
  int lsch  = (lane & 7) ^ lrow;
  const unsigned short* ag[4];
  int loffA[4];
#pragma unroll
  for (int s = 0; s < 4; s++) {
    int r  = wave * 32 + s * 8;
    int p  = sp[r + lrow];
    ag[s] = Abase + (size_t)(AROWDIV4 ? (p >> 2) : p) * KDIM + lsch * 8;
    loffA[s] = r * 64;
  }

  // --- B staging (native layout, subtiled via pre-permuted source) ---
  int bk = (lane >> 1) & 3;
  int bn = (lane >> 3) * 16 + (lane & 1) * 8;
  const unsigned short* bg[4];
  int loffB[4];
#pragma unroll
  for (int s = 0; s < 4; s++) {
    int krow = wave * 16 + s * 4 + bk;         // tile-local k row
    bg[s] = Bbase + ((size_t)e * KDIM + krow) * NDIM + n0 + bn;
    loffB[s] = (wave * 4 + s) * 512;           // elems (kb block = 512 elems)
  }

  int m16  = lane & 15;
  int quad = lane >> 4;
  int wm   = (wave >> 1) * 64;
  int wn   = (wave & 1) * 64;
  int rsw  = (m16 & 7);
  unsigned trB = ldsaddr(sB)
               + (unsigned)(quad * 2048 + (wave & 1) * 512 + m16 * 8);

  floatx4 acc[4][4];
#pragma unroll
  for (int i = 0; i < 4; i++)
#pragma unroll
    for (int j = 0; j < 4; j++) acc[i][j] = (floatx4){0.f, 0.f, 0.f, 0.f};

  for (int k0 = 0; k0 < KDIM; k0 += 64) {
    if (k0) __syncthreads();                   // prev iter's LDS reads done
#pragma unroll
    for (int s = 0; s < 4; s++) gload16(ag[s] + k0, sA + loffA[s]);
#pragma unroll
    for (int s = 0; s < 4; s++) gload16(bg[s] + (size_t)k0 * NDIM, sB + loffB[s]);
    __syncthreads();                           // vmcnt(0) drain: tile landed
#pragma unroll
    for (int ks = 0; ks < 2; ks++) {
      int ch = ((ks * 4 + quad) ^ rsw) * 8;
      short8 af[4];
#pragma unroll
      for (int m = 0; m < 4; m++)
        af[m] = *(const short8*)(sA + (wm + m * 16 + m16) * 64 + ch);
      short8 bf[4];
#pragma unroll
      for (int nt = 0; nt < 4; nt++) {
        union { short4v h[2]; short8 w; } u;
        u.h[0] = tr8(trB + (unsigned)(ks * 8192 + nt * 128));
        u.h[1] = tr8(trB + (unsigned)(ks * 8192 + 1024 + nt * 128));
        bf[nt] = u.w;
      }
      asm volatile("s_waitcnt lgkmcnt(0)" ::: "memory");
      __builtin_amdgcn_sched_barrier(0);
#pragma unroll
      for (int m = 0; m < 4; m++)
#pragma unroll
        for (int n = 0; n < 4; n++)
          acc[m][n] = __builtin_amdgcn_mfma_f32_16x16x32_bf16(af[m], bf[n], acc[m][n], 0, 0, 0);
    }
  }

  // epilogue: C/D col = lane&15 (-> n dim), row = quad*4 + reg (-> m dim)
#pragma unroll
  for (int m = 0; m < 4; m++) {
#pragma unroll
    for (int r = 0; r < 4; r++) {
      int row_local = wm + m * 16 + quad * 4 + r;
      int rg = mt * 128 + row_local;
      if (rg < count) {
        int p = sp[row_local];
#pragma unroll
        for (int n = 0; n < 4; n++) {
          int col = n0 + wn + n * 16 + m16;
          float v = acc[m][n][r];
          if (HASBIAS) v += bf2f(biasAll[e * NDIM + col]);
          if (GELU)    v = 0.5f * v * (1.f + erff(v * 0.70710678118654752f));
          if (OUTF32) outF[(size_t)p * NDIM + col] = v;
          else        outB[(size_t)p * NDIM + col] = f2bf(v);
        }
      }
    }
  }
}

// ---------------- K3: LayerNorm per pair, combine weight folded in ----------
__global__ __launch_bounds__(256) void ln_kernel(
    unsigned short* __restrict__ Hbuf,
    const unsigned short* __restrict__ lnwO, const unsigned short* __restrict__ lnwC,
    const unsigned short* __restrict__ lnbO, const unsigned short* __restrict__ lnbC,
    const int* __restrict__ psel, const float* __restrict__ pw,
    const int* __restrict__ flag)
{
  int p = blockIdx.x;
  int tid = threadIdx.x;
  int e = psel[p];
  int isbf = *flag;
  const unsigned short* lnw = isbf ? lnwO : lnwC;
  const unsigned short* lnb = isbf ? lnbO : lnbC;
  unsigned short* hr = Hbuf + (size_t)p * H_FFN;
  bool act = tid < 192;
  float v[8];
  float s = 0.f, sq = 0.f;
  if (act) {
    ushort8 hv = *(const ushort8*)(hr + tid * 8);
#pragma unroll
    for (int j = 0; j < 8; j++) { v[j] = bf2f(hv[j]); s += v[j]; sq += v[j] * v[j]; }
  }
#pragma unroll
  for (int off = 32; off > 0; off >>= 1) {
    s  += __shfl_down(s, off);
    sq += __shfl_down(sq, off);
  }
  __shared__ float red[8];
  int wave = tid >> 6, lane = tid & 63;
  if (lane == 0) { red[wave * 2] = s; red[wave * 2 + 1] = sq; }
  __syncthreads();
  __shared__ float mv[2];
  if (tid == 0) {
    float S = 0.f, Q = 0.f;
    for (int w = 0; w < 4; w++) { S += red[w * 2]; Q += red[w * 2 + 1]; }
    float mu  = S * (1.f / H_FFN);
    float var = Q * (1.f / H_FFN) - mu * mu;
    mv[0] = mu; mv[1] = rsqrtf(var + 1e-5f);
  }
  __syncthreads();
  if (act) {
    float mu = mv[0], rstd = mv[1];
    float w = pw[p];
    ushort8 lw = *(const ushort8*)(lnw + e * H_FFN + tid * 8);
    ushort8 lb = *(const ushort8*)(lnb + e * H_FFN + tid * 8);
    ushort8 o;
#pragma unroll
    for (int j = 0; j < 8; j++)
      o[j] = f2bf(((v[j] - mu) * rstd * bf2f(lw[j]) + bf2f(lb[j])) * w);
    *(ushort8*)(hr + tid * 8) = o;
  }
}

// ---------------- K5: sum 4 pair outputs + weighted fc2 bias ----------------
__global__ __launch_bounds__(192) void combine_kernel(
    const float* __restrict__ Y,
    const unsigned short* __restrict__ b2O, const unsigned short* __restrict__ b2C,
    const int* __restrict__ psel, const float* __restrict__ pw,
    unsigned short* __restrict__ out16, float* __restrict__ out32,
    const int* __restrict__ flag)
{
  int t = blockIdx.x;
  int tid = threadIdx.x;                       // 192 threads, 192*4 = 768
  int isbf = *flag;
  const unsigned short* b2 = isbf ? b2O : b2C;
  int e1 = psel[t * 4 + 1], e2 = psel[t * 4 + 2], e3 = psel[t * 4 + 3];
  float w1 = pw[t * 4 + 1], w2 = pw[t * 4 + 2], w3 = pw[t * 4 + 3];
  int d = tid * 4;
  const float* Yb = Y + (size_t)t * 4 * D_EMB + d;
  floatx4 y0 = *(const floatx4*)(Yb);
  floatx4 y1 = *(const floatx4*)(Yb + D_EMB);
  floatx4 y2 = *(const floatx4*)(Yb + 2 * D_EMB);
  floatx4 y3 = *(const floatx4*)(Yb + 3 * D_EMB);
  ushort4v b0 = *(const ushort4v*)(b2 + d);
  ushort4v bb1 = *(const ushort4v*)(b2 + e1 * D_EMB + d);
  ushort4v bb2 = *(const ushort4v*)(b2 + e2 * D_EMB + d);
  ushort4v bb3 = *(const ushort4v*)(b2 + e3 * D_EMB + d);
  if (isbf) {
    ushort4v o;
#pragma unroll
    for (int j = 0; j < 4; j++) {
      float a = y0[j] + y1[j] + y2[j] + y3[j] + bf2f(b0[j])
              + w1 * bf2f(bb1[j]) + w2 * bf2f(bb2[j]) + w3 * bf2f(bb3[j]);
      o[j] = f2bf(a);
    }
    *(ushort4v*)(out16 + (size_t)t * D_EMB + d) = o;
  } else {
    floatx4 o;
#pragma unroll
    for (int j = 0; j < 4; j++)
      o[j] = y0[j] + y1[j] + y2[j] + y3[j] + bf2f(b0[j])
           + w1 * bf2f(bb1[j]) + w2 * bf2f(bb2[j]) + w3 * bf2f(bb3[j]);
    *(floatx4*)(out32 + (size_t)t * D_EMB + d) = o;
  }
}

extern "C" void kernel_launch(void* const* d_in, const int* in_sizes, int n_in,
                              void* d_out, int out_size, void* d_ws, size_t ws_size,
                              hipStream_t stream)
{
  (void)in_sizes; (void)n_in; (void)out_size; (void)ws_size;
  char* ws = (char*)d_ws;
  int*   cnt   = (int*)ws;                                 // 16 ints
  int*   plist = (int*)(ws + 256);                         // 16*2048 ints
  int*   psel  = (int*)(ws + 131328);                      // 8192 ints
  float* pw    = (float*)(ws + 164096);                    // 8192 f32
  int*   flag  = (int*)(ws + 196864);
  unsigned short* fc1bC = (unsigned short*)(ws + 197120);  // 24576 bf16
  unsigned short* lnwC  = (unsigned short*)(ws + 246272);
  unsigned short* lnbC  = (unsigned short*)(ws + 295424);
  unsigned short* fc2bC = (unsigned short*)(ws + 344576);  // 12288 bf16
  unsigned short* xC    = (unsigned short*)(ws + 524288);  // 1572864 bf16
  unsigned short* Hbuf  = (unsigned short*)(ws + 3670016); // 8192*1536 bf16
  float*          Ybuf  = (float*)(ws + 28835840);         // 8192*768 f32
  unsigned short* wsW1  = (unsigned short*)(ws + 54001664);// [16][768][1536] bf16
  unsigned short* wsW2  = (unsigned short*)(ws + 91750400);// [16][1536][768] bf16

  hipMemsetAsync(cnt, 0, 64, stream);                      // zero expert counters

  prep_kernel<<<NW1 + NW2 + NX + NB + NGATE, 256, 0, stream>>>(
      (const unsigned int*)d_in[0],
      (const unsigned short*)d_in[0], (const float*)d_in[0],
      (const unsigned short*)d_in[1], (const float*)d_in[1],
      (const unsigned short*)d_in[2], (const float*)d_in[2],
      (const float*)d_in[3], (const float*)d_in[7],
      (const float*)d_in[4], (const float*)d_in[5],
      (const float*)d_in[6], (const float*)d_in[8],
      xC, wsW1, wsW2,
      fc1bC, lnwC, lnbC, fc2bC,
      flag, psel, pw, cnt, plist);

  moe_gemm<D_EMB, H_FFN, true, true, true, false>
      <<<NE * 16 * (H_FFN / 128), 256, 0, stream>>>(
      (const unsigned short*)d_in[0], xC,
      (const unsigned short*)d_in[3], wsW1,
      (const unsigned short*)d_in[4], fc1bC,
      flag, cnt, plist, Hbuf, nullptr);

  ln_kernel<<<NPAIR, 256, 0, stream>>>(
      Hbuf,
      (const unsigned short*)d_in[5], lnwC,
      (const unsigned short*)d_in[6], lnbC,
      psel, pw, flag);

  moe_gemm<H_FFN, D_EMB, false, false, false, true>
      <<<NE * 16 * (D_EMB / 128), 256, 0, stream>>>(
      Hbuf, Hbuf,
      (const unsigned short*)d_in[7], wsW2,
      nullptr, nullptr,
      flag, cnt, plist, nullptr, Ybuf);

  combine_kernel<<<T_TOK, 192, 0, stream>>>(
      Ybuf,
      (const unsigned short*)d_in[8], fc2bC,
      psel, pw,
      (unsigned short*)d_out, (float*)d_out, flag);
}

// Round 9
// 342.677 us; speedup vs baseline: 1.1790x; 1.0236x over previous
//
#include <hip/hip_runtime.h>
#include <cmath>

#define T_TOK 2048
#define D_EMB 768
#define H_FFN 1536
#define NE    16
#define NPAIR (T_TOK * 4)

// prep_kernel block-range partition (gate FIRST so it overlaps conv stream)
#define NGATE 512                  // gating: 4 tokens per block
#define NX    768                  // x f32->bf16: 768*256*8 = 1,572,864
#define NB    12                   // biases: 12*256*8 = 24576
#define NW1B  2304                 // fc1_w f32->bf16, grid-strided 4 chunks/blk
// W2 conversion rides inside the fc1 moe_gemm grid (see CONVW2 below).
#define NW2B  2304

typedef __attribute__((ext_vector_type(8))) short          short8;
typedef __attribute__((ext_vector_type(4))) short          short4v;
typedef __attribute__((ext_vector_type(8))) unsigned short ushort8;
typedef __attribute__((ext_vector_type(4))) unsigned short ushort4v;
typedef __attribute__((ext_vector_type(4))) float          floatx4;

__device__ __forceinline__ float bf2f(unsigned short u) {
  union { unsigned int i; float f; } v; v.i = ((unsigned int)u) << 16; return v.f;
}
__device__ __forceinline__ unsigned short f2bf(float f) {
  union { float f; unsigned int i; } v; v.f = f;
  unsigned int r = v.i + 0x7fffu + ((v.i >> 16) & 1u);   // RNE
  return (unsigned short)(r >> 16);
}

// async global->LDS, 16B per lane. LDS dest is wave-uniform base + lane*16.
__device__ __forceinline__ void gload16(const unsigned short* g, unsigned short* l) {
  __builtin_amdgcn_global_load_lds(
      (const __attribute__((address_space(1))) unsigned int*)g,
      (__attribute__((address_space(3))) unsigned int*)l,
      16, 0, 0);
}

// 32-bit LDS byte offset of a __shared__ pointer
__device__ __forceinline__ unsigned ldsaddr(const void* p) {
  return (unsigned)(unsigned long long)
      (const __attribute__((address_space(3))) char*)p;
}

// hardware transpose read (cross-lane within each 16-lane group):
// each lane fetches 8B at its own vaddr; the group's 128B (a 4x16 bf16
// row-major tile when vaddr = tile_base + (l&15)*8) is redistributed so
// lane l's 4 elems = column (l&15): tile[j*16 + (l&15)], j=0..3.
__device__ __forceinline__ short4v tr8(unsigned a) {
  short4v d;
  asm volatile("ds_read_b64_tr_b16 %0, %1" : "=v"(d) : "v"(a));
  return d;
}

// per-block dtype sniff: 256 threads x 2 words; deterministic across blocks.
__device__ __forceinline__ int block_sniff(const unsigned int* __restrict__ xw, int tid) {
  int c = 0;
#pragma unroll
  for (int i = 0; i < 2; i++) {
    unsigned int w = xw[tid * 2 + i];
    unsigned int e = (w >> 7) & 0xFFu;
    c += (e >= 100u && e <= 140u) ? 1 : 0;
  }
#pragma unroll
  for (int off = 32; off > 0; off >>= 1) c += __shfl_down(c, off);
  __shared__ int ssn[4];
  int wave = tid >> 6, lane = tid & 63;
  if (lane == 0) ssn[wave] = c;
  __syncthreads();
  return (ssn[0] + ssn[1] + ssn[2] + ssn[3] > 300) ? 1 : 0;
}

__device__ __forceinline__ void conv8(const float* __restrict__ src,
                                      unsigned short* __restrict__ dst, size_t i) {
  floatx4 a = *(const floatx4*)(src + i);
  floatx4 b = *(const floatx4*)(src + i + 4);
  ushort8 o;
#pragma unroll
  for (int j = 0; j < 4; j++) { o[j] = f2bf(a[j]); o[4 + j] = f2bf(b[j]); }
  *(ushort8*)(dst + i) = o;
}

// ---------------- K_PREP: fused sniff + gate + convert(x, biases, W1) -------
// W2 conversion is embedded in the fc1 GEMM grid (stream order guarantees it
// completes before fc2 consumes it). Gate blocks dispatched first so they
// overlap the conv stream instead of trailing. W1 conv grid-strided 4x so
// the per-block sniff/latency overhead amortizes and loads pipeline.
__global__ __launch_bounds__(256) void prep_kernel(
    const unsigned int* __restrict__ xw,
    const unsigned short* __restrict__ x16, const float* __restrict__ x32,
    const unsigned short* __restrict__ gw16, const float* __restrict__ gw32,
    const unsigned short* __restrict__ gb16, const float* __restrict__ gb32,
    const float* __restrict__ w1F,
    const float* __restrict__ fc1bF, const float* __restrict__ lnwF,
    const float* __restrict__ lnbF, const float* __restrict__ fc2bF,
    unsigned short* __restrict__ xC,
    unsigned short* __restrict__ wsW1,
    unsigned short* __restrict__ dfc1b, unsigned short* __restrict__ dlnw,
    unsigned short* __restrict__ dlnb, unsigned short* __restrict__ dfc2b,
    int* __restrict__ flagOut,
    int* __restrict__ psel, float* __restrict__ pw,
    int* __restrict__ cnt, int* __restrict__ plist)
{
  __shared__ __align__(16) float sacc[4][64][17];
  int bid = blockIdx.x;
  int tid = threadIdx.x;
  int isbf = block_sniff(xw, tid);
  if (bid == 0 && tid == 0) *flagOut = isbf;

  if (bid < NGATE) {
    // ---- gate: 4 waves, one token each ----
    int wave = tid >> 6, lane = tid & 63;
    int t = bid * 4 + wave;
    float acc[NE];
#pragma unroll
    for (int e = 0; e < NE; e++) acc[e] = 0.f;
    if (isbf) {
#pragma unroll
      for (int i = 0; i < D_EMB / 64; i++) {
        int d = i * 64 + lane;
        float xv = bf2f(x16[(size_t)t * D_EMB + d]);
        ushort8 g0 = *(const ushort8*)(gw16 + d * NE);
        ushort8 g1 = *(const ushort8*)(gw16 + d * NE + 8);
#pragma unroll
        for (int e = 0; e < 8; e++) acc[e]     += xv * bf2f(g0[e]);
#pragma unroll
        for (int e = 0; e < 8; e++) acc[8 + e] += xv * bf2f(g1[e]);
      }
    } else {
#pragma unroll
      for (int i = 0; i < D_EMB / 64; i++) {
        int d = i * 64 + lane;
        float xv = x32[(size_t)t * D_EMB + d];
#pragma unroll
        for (int q = 0; q < 4; q++) {
          floatx4 g = *(const floatx4*)(gw32 + d * NE + q * 4);
#pragma unroll
          for (int j = 0; j < 4; j++) acc[q * 4 + j] += xv * g[j];
        }
      }
    }
#pragma unroll
    for (int e = 0; e < NE; e++) sacc[wave][lane][e] = acc[e];
    __syncthreads();
    int e = lane & 15, q = lane >> 4;
    float s = 0.f;
#pragma unroll
    for (int i = 0; i < 16; i++) s += sacc[wave][q * 16 + i][e];
    s += __shfl_xor(s, 16);
    s += __shfl_xor(s, 32);
    float sv = s + (isbf ? bf2f(gb16[e]) : gb32[e]);
    if (e == 0) sv = -1e9f;
    float m = sv;
#pragma unroll
    for (int off = 8; off > 0; off >>= 1) m = fmaxf(m, __shfl_xor(m, off));
    float pe = expf(sv - m);
    float den = pe;
#pragma unroll
    for (int off = 8; off > 0; off >>= 1) den += __shfl_xor(den, off);
    float pr = pe / den;
    float val = (e == 0) ? -1.f : pr;
    int sel0, sel1, sel2; float sw0, sw1, sw2;
#pragma unroll
    for (int k = 0; k < 3; k++) {
      float bv = val; int bi = e;
#pragma unroll
      for (int off = 8; off > 0; off >>= 1) {
        float ov = __shfl_xor(bv, off);
        int   oi = __shfl_xor(bi, off);
        if (ov > bv || (ov == bv && oi < bi)) { bv = ov; bi = oi; }
      }
      if (k == 0) { sel0 = bi; sw0 = bv; }
      else if (k == 1) { sel1 = bi; sw1 = bv; }
      else { sel2 = bi; sw2 = bv; }
      if (e == bi) val = -1.f;
    }
    if (lane < 4) {
      int se; float swt;
      if (lane == 0)      { se = 0;    swt = 1.0f; }
      else if (lane == 1) { se = sel0; swt = sw0; }
      else if (lane == 2) { se = sel1; swt = sw1; }
      else                { se = sel2; swt = sw2; }
      int pidx = t * 4 + lane;
      psel[pidx] = se; pw[pidx] = swt;
      int pos = atomicAdd(&cnt[se], 1);
      plist[se * T_TOK + pos] = pidx;
    }
  } else if (bid < NGATE + NX) {
    if (!isbf) conv8(x32, xC, ((size_t)(bid - NGATE) * 256 + tid) * 8);
  } else if (bid < NGATE + NX + NB) {
    if (!isbf) {
      size_t g = (size_t)(bid - NGATE - NX) * 256 + tid;   // [0, 3072)
      size_t i = g * 8;
      conv8(fc1bF, dfc1b, i);
      conv8(lnwF,  dlnw,  i);
      conv8(lnbF,  dlnb,  i);
      if (g < 1536) conv8(fc2bF, dfc2b, i);
    }
  } else {
    if (!isbf) {
      int cb = bid - (NGATE + NX + NB);        // 0..2303, 4 chunks each
#pragma unroll
      for (int it = 0; it < 4; it++)
        conv8(w1F, wsW1, ((size_t)(cb * 4 + it) * 256 + tid) * 8);
    }
  }
}

// ---------------- K2/K4: grouped GEMM, NATIVE-layout B via tr-reads ---------
// Block tile 128x128, BK=64, single LDS buffer. 4 waves as 2x2 -> 64x64.
// A: gathered rows, k-contiguous, XOR-swizzled source+read.
// B: native [e][KDIM][NDIM]. Staged subtiled: elem (k,n) of the 64x128 tile at
//   LDS idx (k>>2)*512 + (n>>4)*64 + (k&3)*16 + (n&15), via linear LDS dest +
//   permuted per-lane GLOBAL source; consumed with ds_read_b64_tr_b16
//   (vaddr = sB + ks*8192 + quad*2048 + (wave&1)*512 + nt*128 + m16*8,
//    second half at +1024).
// CONVW2: extra trailing blocks convert fc2_w f32->bf16 concurrently with the
// fc1 GEMM (fc2 consumes it only after ln -> stream order safe).
template<int KDIM, int NDIM, bool GELU, bool HASBIAS, bool AROWDIV4, bool OUTF32,
         bool CONVW2>
__global__ __launch_bounds__(256) void moe_gemm(
    const unsigned short* __restrict__ AO, const unsigned short* __restrict__ AC,
    const unsigned short* __restrict__ BO, const unsigned short* __restrict__ BC,
    const unsigned short* __restrict__ biasO, const unsigned short* __restrict__ biasC,
    const float* __restrict__ w2F, unsigned short* __restrict__ w2D,
    const int* __restrict__ flag,
    const int* __restrict__ cnt, const int* __restrict__ plist,
    unsigned short* __restrict__ outB, float* __restrict__ outF)
{
  const int NSP = NDIM / 128;
  int bx  = blockIdx.x;
  int tid = threadIdx.x;
  if (CONVW2) {
    const int nblk = NE * 16 * NSP;
    if (bx >= nblk) {
      if (!*flag) {
        int cb = bx - nblk;                    // 0..NW2B-1, 4 chunks each
#pragma unroll
        for (int it = 0; it < 4; it++)
          conv8(w2F, w2D, ((size_t)(cb * 4 + it) * 256 + tid) * 8);
      }
      return;
    }
  }
  int e   = bx / (16 * NSP);
  int rem = bx % (16 * NSP);
  int mt  = rem / NSP;
  int ns  = rem % NSP;
  int count = cnt[e];
  if (mt * 128 >= count) return;
  const unsigned short* Abase   = (*flag) ? AO : AC;
  const unsigned short* Bbase   = (*flag) ? BO : BC;
  const unsigned short* biasAll = (*flag) ? biasO : biasC;

  __shared__ __align__(16) unsigned short sA[128 * 64];
  __shared__ __align__(16) unsigned short sB[64 * 128];   // subtiled
  __shared__ int sp[128];

  if (tid < 128) {
    int rg  = mt * 128 + tid;
    int idx = rg < count ? rg : count - 1;    // duplicate last row (pad)
    sp[tid] = plist[e * T_TOK + idx];
  }
  __syncthreads();

  int lane = tid & 63;
  int wave = tid >> 6;
  int n0   = ns * 128;

  // --- A staging (XOR chunk swizzle on source + read) ---
  int lrow  = lane >> 3;
  int lsch  = (lane & 7) ^ lrow;
  const unsigned short* ag[4];
  int loffA[4];
#pragma unroll
  for (int s = 0; s < 4; s++) {
    int r  = wave * 32 + s * 8;
    int p  = sp[r + lrow];
    ag[s] = Abase + (size_t)(AROWDIV4 ? (p >> 2) : p) * KDIM + lsch * 8;
    loffA[s] = r * 64;
  }

  // --- B staging (native layout, subtiled via pre-permuted source) ---
  int bk = (lane >> 1) & 3;
  int bn = (lane >> 3) * 16 + (lane & 1) * 8;
  const unsigned short* bg[4];
  int loffB[4];
#pragma unroll
  for (int s = 0; s < 4; s++) {
    int krow = wave * 16 + s * 4 + bk;         // tile-local k row
    bg[s] = Bbase + ((size_t)e * KDIM + krow) * NDIM + n0 + bn;
    loffB[s] = (wave * 4 + s) * 512;           // elems (kb block = 512 elems)
  }

  int m16  = lane & 15;
  int quad = lane >> 4;
  int wm   = (wave >> 1) * 64;
  int wn   = (wave & 1) * 64;
  int rsw  = (m16 & 7);
  unsigned trB = ldsaddr(sB)
               + (unsigned)(quad * 2048 + (wave & 1) * 512 + m16 * 8);

  floatx4 acc[4][4];
#pragma unroll
  for (int i = 0; i < 4; i++)
#pragma unroll
    for (int j = 0; j < 4; j++) acc[i][j] = (floatx4){0.f, 0.f, 0.f, 0.f};

  for (int k0 = 0; k0 < KDIM; k0 += 64) {
    if (k0) __syncthreads();                   // prev iter's LDS reads done
#pragma unroll
    for (int s = 0; s < 4; s++) gload16(ag[s] + k0, sA + loffA[s]);
#pragma unroll
    for (int s = 0; s < 4; s++) gload16(bg[s] + (size_t)k0 * NDIM, sB + loffB[s]);
    __syncthreads();                           // vmcnt(0) drain: tile landed
#pragma unroll
    for (int ks = 0; ks < 2; ks++) {
      int ch = ((ks * 4 + quad) ^ rsw) * 8;
      short8 af[4];
#pragma unroll
      for (int m = 0; m < 4; m++)
        af[m] = *(const short8*)(sA + (wm + m * 16 + m16) * 64 + ch);
      short8 bf[4];
#pragma unroll
      for (int nt = 0; nt < 4; nt++) {
        union { short4v h[2]; short8 w; } u;
        u.h[0] = tr8(trB + (unsigned)(ks * 8192 + nt * 128));
        u.h[1] = tr8(trB + (unsigned)(ks * 8192 + 1024 + nt * 128));
        bf[nt] = u.w;
      }
      asm volatile("s_waitcnt lgkmcnt(0)" ::: "memory");
      __builtin_amdgcn_sched_barrier(0);
#pragma unroll
      for (int m = 0; m < 4; m++)
#pragma unroll
        for (int n = 0; n < 4; n++)
          acc[m][n] = __builtin_amdgcn_mfma_f32_16x16x32_bf16(af[m], bf[n], acc[m][n], 0, 0, 0);
    }
  }

  // epilogue: C/D col = lane&15 (-> n dim), row = quad*4 + reg (-> m dim)
#pragma unroll
  for (int m = 0; m < 4; m++) {
#pragma unroll
    for (int r = 0; r < 4; r++) {
      int row_local = wm + m * 16 + quad * 4 + r;
      int rg = mt * 128 + row_local;
      if (rg < count) {
        int p = sp[row_local];
#pragma unroll
        for (int n = 0; n < 4; n++) {
          int col = n0 + wn + n * 16 + m16;
          float v = acc[m][n][r];
          if (HASBIAS) v += bf2f(biasAll[e * NDIM + col]);
          if (GELU)    v = 0.5f * v * (1.f + erff(v * 0.70710678118654752f));
          if (OUTF32) outF[(size_t)p * NDIM + col] = v;
          else        outB[(size_t)p * NDIM + col] = f2bf(v);
        }
      }
    }
  }
}

// ---------------- K3: LayerNorm per pair, combine weight folded in ----------
__global__ __launch_bounds__(256) void ln_kernel(
    unsigned short* __restrict__ Hbuf,
    const unsigned short* __restrict__ lnwO, const unsigned short* __restrict__ lnwC,
    const unsigned short* __restrict__ lnbO, const unsigned short* __restrict__ lnbC,
    const int* __restrict__ psel, const float* __restrict__ pw,
    const int* __restrict__ flag)
{
  int p = blockIdx.x;
  int tid = threadIdx.x;
  int e = psel[p];
  int isbf = *flag;
  const unsigned short* lnw = isbf ? lnwO : lnwC;
  const unsigned short* lnb = isbf ? lnbO : lnbC;
  unsigned short* hr = Hbuf + (size_t)p * H_FFN;
  bool act = tid < 192;
  float v[8];
  float s = 0.f, sq = 0.f;
  if (act) {
    ushort8 hv = *(const ushort8*)(hr + tid * 8);
#pragma unroll
    for (int j = 0; j < 8; j++) { v[j] = bf2f(hv[j]); s += v[j]; sq += v[j] * v[j]; }
  }
#pragma unroll
  for (int off = 32; off > 0; off >>= 1) {
    s  += __shfl_down(s, off);
    sq += __shfl_down(sq, off);
  }
  __shared__ float red[8];
  int wave = tid >> 6, lane = tid & 63;
  if (lane == 0) { red[wave * 2] = s; red[wave * 2 + 1] = sq; }
  __syncthreads();
  __shared__ float mv[2];
  if (tid == 0) {
    float S = 0.f, Q = 0.f;
    for (int w = 0; w < 4; w++) { S += red[w * 2]; Q += red[w * 2 + 1]; }
    float mu  = S * (1.f / H_FFN);
    float var = Q * (1.f / H_FFN) - mu * mu;
    mv[0] = mu; mv[1] = rsqrtf(var + 1e-5f);
  }
  __syncthreads();
  if (act) {
    float mu = mv[0], rstd = mv[1];
    float w = pw[p];
    ushort8 lw = *(const ushort8*)(lnw + e * H_FFN + tid * 8);
    ushort8 lb = *(const ushort8*)(lnb + e * H_FFN + tid * 8);
    ushort8 o;
#pragma unroll
    for (int j = 0; j < 8; j++)
      o[j] = f2bf(((v[j] - mu) * rstd * bf2f(lw[j]) + bf2f(lb[j])) * w);
    *(ushort8*)(hr + tid * 8) = o;
  }
}

// ---------------- K5: sum 4 pair outputs + weighted fc2 bias ----------------
__global__ __launch_bounds__(192) void combine_kernel(
    const float* __restrict__ Y,
    const unsigned short* __restrict__ b2O, const unsigned short* __restrict__ b2C,
    const int* __restrict__ psel, const float* __restrict__ pw,
    unsigned short* __restrict__ out16, float* __restrict__ out32,
    const int* __restrict__ flag)
{
  int t = blockIdx.x;
  int tid = threadIdx.x;                       // 192 threads, 192*4 = 768
  int isbf = *flag;
  const unsigned short* b2 = isbf ? b2O : b2C;
  int e1 = psel[t * 4 + 1], e2 = psel[t * 4 + 2], e3 = psel[t * 4 + 3];
  float w1 = pw[t * 4 + 1], w2 = pw[t * 4 + 2], w3 = pw[t * 4 + 3];
  int d = tid * 4;
  const float* Yb = Y + (size_t)t * 4 * D_EMB + d;
  floatx4 y0 = *(const floatx4*)(Yb);
  floatx4 y1 = *(const floatx4*)(Yb + D_EMB);
  floatx4 y2 = *(const floatx4*)(Yb + 2 * D_EMB);
  floatx4 y3 = *(const floatx4*)(Yb + 3 * D_EMB);
  ushort4v b0 = *(const ushort4v*)(b2 + d);
  ushort4v bb1 = *(const ushort4v*)(b2 + e1 * D_EMB + d);
  ushort4v bb2 = *(const ushort4v*)(b2 + e2 * D_EMB + d);
  ushort4v bb3 = *(const ushort4v*)(b2 + e3 * D_EMB + d);
  if (isbf) {
    ushort4v o;
#pragma unroll
    for (int j = 0; j < 4; j++) {
      float a = y0[j] + y1[j] + y2[j] + y3[j] + bf2f(b0[j])
              + w1 * bf2f(bb1[j]) + w2 * bf2f(bb2[j]) + w3 * bf2f(bb3[j]);
      o[j] = f2bf(a);
    }
    *(ushort4v*)(out16 + (size_t)t * D_EMB + d) = o;
  } else {
    floatx4 o;
#pragma unroll
    for (int j = 0; j < 4; j++)
      o[j] = y0[j] + y1[j] + y2[j] + y3[j] + bf2f(b0[j])
           + w1 * bf2f(bb1[j]) + w2 * bf2f(bb2[j]) + w3 * bf2f(bb3[j]);
    *(floatx4*)(out32 + (size_t)t * D_EMB + d) = o;
  }
}

extern "C" void kernel_launch(void* const* d_in, const int* in_sizes, int n_in,
                              void* d_out, int out_size, void* d_ws, size_t ws_size,
                              hipStream_t stream)
{
  (void)in_sizes; (void)n_in; (void)out_size; (void)ws_size;
  char* ws = (char*)d_ws;
  int*   cnt   = (int*)ws;                                 // 16 ints
  int*   plist = (int*)(ws + 256);                         // 16*2048 ints
  int*   psel  = (int*)(ws + 131328);                      // 8192 ints
  float* pw    = (float*)(ws + 164096);                    // 8192 f32
  int*   flag  = (int*)(ws + 196864);
  unsigned short* fc1bC = (unsigned short*)(ws + 197120);  // 24576 bf16
  unsigned short* lnwC  = (unsigned short*)(ws + 246272);
  unsigned short* lnbC  = (unsigned short*)(ws + 295424);
  unsigned short* fc2bC = (unsigned short*)(ws + 344576);  // 12288 bf16
  unsigned short* xC    = (unsigned short*)(ws + 524288);  // 1572864 bf16
  unsigned short* Hbuf  = (unsigned short*)(ws + 3670016); // 8192*1536 bf16
  float*          Ybuf  = (float*)(ws + 28835840);         // 8192*768 f32
  unsigned short* wsW1  = (unsigned short*)(ws + 54001664);// [16][768][1536] bf16
  unsigned short* wsW2  = (unsigned short*)(ws + 91750400);// [16][1536][768] bf16

  hipMemsetAsync(cnt, 0, 64, stream);                      // zero expert counters

  prep_kernel<<<NGATE + NX + NB + NW1B, 256, 0, stream>>>(
      (const unsigned int*)d_in[0],
      (const unsigned short*)d_in[0], (const float*)d_in[0],
      (const unsigned short*)d_in[1], (const float*)d_in[1],
      (const unsigned short*)d_in[2], (const float*)d_in[2],
      (const float*)d_in[3],
      (const float*)d_in[4], (const float*)d_in[5],
      (const float*)d_in[6], (const float*)d_in[8],
      xC, wsW1,
      fc1bC, lnwC, lnbC, fc2bC,
      flag, psel, pw, cnt, plist);

  moe_gemm<D_EMB, H_FFN, true, true, true, false, true>
      <<<NE * 16 * (H_FFN / 128) + NW2B, 256, 0, stream>>>(
      (const unsigned short*)d_in[0], xC,
      (const unsigned short*)d_in[3], wsW1,
      (const unsigned short*)d_in[4], fc1bC,
      (const float*)d_in[7], wsW2,
      flag, cnt, plist, Hbuf, nullptr);

  ln_kernel<<<NPAIR, 256, 0, stream>>>(
      Hbuf,
      (const unsigned short*)d_in[5], lnwC,
      (const unsigned short*)d_in[6], lnbC,
      psel, pw, flag);

  moe_gemm<H_FFN, D_EMB, false, false, false, true, false>
      <<<NE * 16 * (D_EMB / 128), 256, 0, stream>>>(
      Hbuf, Hbuf,
      (const unsigned short*)d_in[7], wsW2,
      nullptr, nullptr,
      nullptr, nullptr,
      flag, cnt, plist, nullptr, Ybuf);

  combine_kernel<<<T_TOK, 192, 0, stream>>>(
      Ybuf,
      (const unsigned short*)d_in[8], fc2bC,
      psel, pw,
      (unsigned short*)d_out, (float*)d_out, flag);
}

// Round 10
// 310.203 us; speedup vs baseline: 1.3024x; 1.1047x over previous
//
#include <hip/hip_runtime.h>
#include <cmath>

#define T_TOK 2048
#define D_EMB 768
#define H_FFN 1536
#define NE    16
#define NPAIR (T_TOK * 4)

// prep_kernel block-range partition (gate FIRST so it overlaps conv stream)
#define NGATE 512                  // gating: 4 tokens per block
#define NX    768                  // x f32->bf16: 768*256*8 = 1,572,864
#define NB    12                   // biases: 12*256*8 = 24576
#define NW1B  2304                 // fc1_w f32->bf16, grid-strided 4 chunks/blk
// W2 conversion rides inside the fc1 moe_gemm grid (see CONVW2 below).
#define NW2B  2304

typedef __attribute__((ext_vector_type(8))) short          short8;
typedef __attribute__((ext_vector_type(4))) short          short4v;
typedef __attribute__((ext_vector_type(8))) unsigned short ushort8;
typedef __attribute__((ext_vector_type(4))) unsigned short ushort4v;
typedef __attribute__((ext_vector_type(4))) float          floatx4;

__device__ __forceinline__ float bf2f(unsigned short u) {
  union { unsigned int i; float f; } v; v.i = ((unsigned int)u) << 16; return v.f;
}
__device__ __forceinline__ unsigned short f2bf(float f) {
  union { float f; unsigned int i; } v; v.f = f;
  unsigned int r = v.i + 0x7fffu + ((v.i >> 16) & 1u);   // RNE
  return (unsigned short)(r >> 16);
}

// async global->LDS, 16B per lane. LDS dest is wave-uniform base + lane*16.
__device__ __forceinline__ void gload16(const unsigned short* g, unsigned short* l) {
  __builtin_amdgcn_global_load_lds(
      (const __attribute__((address_space(1))) unsigned int*)g,
      (__attribute__((address_space(3))) unsigned int*)l,
      16, 0, 0);
}

// 32-bit LDS byte offset of a __shared__ pointer
__device__ __forceinline__ unsigned ldsaddr(const void* p) {
  return (unsigned)(unsigned long long)
      (const __attribute__((address_space(3))) char*)p;
}

// hardware transpose read (cross-lane within each 16-lane group):
// each lane fetches 8B at its own vaddr; the group's 128B (a 4x16 bf16
// row-major tile when vaddr = tile_base + (l&15)*8) is redistributed so
// lane l's 4 elems = column (l&15): tile[j*16 + (l&15)], j=0..3.
__device__ __forceinline__ short4v tr8(unsigned a) {
  short4v d;
  asm volatile("ds_read_b64_tr_b16 %0, %1" : "=v"(d) : "v"(a));
  return d;
}

// per-block dtype sniff: 256 threads x 2 words; deterministic across blocks.
__device__ __forceinline__ int block_sniff(const unsigned int* __restrict__ xw, int tid) {
  int c = 0;
#pragma unroll
  for (int i = 0; i < 2; i++) {
    unsigned int w = xw[tid * 2 + i];
    unsigned int e = (w >> 7) & 0xFFu;
    c += (e >= 100u && e <= 140u) ? 1 : 0;
  }
#pragma unroll
  for (int off = 32; off > 0; off >>= 1) c += __shfl_down(c, off);
  __shared__ int ssn[4];
  int wave = tid >> 6, lane = tid & 63;
  if (lane == 0) ssn[wave] = c;
  __syncthreads();
  return (ssn[0] + ssn[1] + ssn[2] + ssn[3] > 300) ? 1 : 0;
}

__device__ __forceinline__ void conv8(const float* __restrict__ src,
                                      unsigned short* __restrict__ dst, size_t i) {
  floatx4 a = *(const floatx4*)(src + i);
  floatx4 b = *(const floatx4*)(src + i + 4);
  ushort8 o;
#pragma unroll
  for (int j = 0; j < 4; j++) { o[j] = f2bf(a[j]); o[4 + j] = f2bf(b[j]); }
  *(ushort8*)(dst + i) = o;
}

// ---------------- K_PREP: fused sniff + gate + convert(x, biases, W1) -------
// W2 conversion is embedded in the fc1 GEMM grid (stream order guarantees it
// completes before fc2 consumes it). Gate blocks dispatched first so they
// overlap the conv stream. Gate uses BLOCK-AGGREGATED expert counters: one
// atomicAdd per expert per block (512-deep chain max) instead of one per
// pair (2048-deep serialized RMW chain on cnt[0]).
__global__ __launch_bounds__(256) void prep_kernel(
    const unsigned int* __restrict__ xw,
    const unsigned short* __restrict__ x16, const float* __restrict__ x32,
    const unsigned short* __restrict__ gw16, const float* __restrict__ gw32,
    const unsigned short* __restrict__ gb16, const float* __restrict__ gb32,
    const float* __restrict__ w1F,
    const float* __restrict__ fc1bF, const float* __restrict__ lnwF,
    const float* __restrict__ lnbF, const float* __restrict__ fc2bF,
    unsigned short* __restrict__ xC,
    unsigned short* __restrict__ wsW1,
    unsigned short* __restrict__ dfc1b, unsigned short* __restrict__ dlnw,
    unsigned short* __restrict__ dlnb, unsigned short* __restrict__ dfc2b,
    int* __restrict__ flagOut,
    int* __restrict__ psel, float* __restrict__ pw,
    int* __restrict__ cnt, int* __restrict__ plist)
{
  __shared__ __align__(16) float sacc[4][64][17];
  int bid = blockIdx.x;
  int tid = threadIdx.x;
  int isbf = block_sniff(xw, tid);
  if (bid == 0 && tid == 0) *flagOut = isbf;

  if (bid < NGATE) {
    // ---- gate: 4 waves, one token each ----
    int wave = tid >> 6, lane = tid & 63;
    int t = bid * 4 + wave;
    float acc[NE];
#pragma unroll
    for (int e = 0; e < NE; e++) acc[e] = 0.f;
    if (isbf) {
#pragma unroll
      for (int i = 0; i < D_EMB / 64; i++) {
        int d = i * 64 + lane;
        float xv = bf2f(x16[(size_t)t * D_EMB + d]);
        ushort8 g0 = *(const ushort8*)(gw16 + d * NE);
        ushort8 g1 = *(const ushort8*)(gw16 + d * NE + 8);
#pragma unroll
        for (int e = 0; e < 8; e++) acc[e]     += xv * bf2f(g0[e]);
#pragma unroll
        for (int e = 0; e < 8; e++) acc[8 + e] += xv * bf2f(g1[e]);
      }
    } else {
#pragma unroll
      for (int i = 0; i < D_EMB / 64; i++) {
        int d = i * 64 + lane;
        float xv = x32[(size_t)t * D_EMB + d];
#pragma unroll
        for (int q = 0; q < 4; q++) {
          floatx4 g = *(const floatx4*)(gw32 + d * NE + q * 4);
#pragma unroll
          for (int j = 0; j < 4; j++) acc[q * 4 + j] += xv * g[j];
        }
      }
    }
#pragma unroll
    for (int e = 0; e < NE; e++) sacc[wave][lane][e] = acc[e];
    __syncthreads();
    int e = lane & 15, q = lane >> 4;
    float s = 0.f;
#pragma unroll
    for (int i = 0; i < 16; i++) s += sacc[wave][q * 16 + i][e];
    s += __shfl_xor(s, 16);
    s += __shfl_xor(s, 32);
    float sv = s + (isbf ? bf2f(gb16[e]) : gb32[e]);
    if (e == 0) sv = -1e9f;
    float m = sv;
#pragma unroll
    for (int off = 8; off > 0; off >>= 1) m = fmaxf(m, __shfl_xor(m, off));
    float pe = expf(sv - m);
    float den = pe;
#pragma unroll
    for (int off = 8; off > 0; off >>= 1) den += __shfl_xor(den, off);
    float pr = pe / den;
    float val = (e == 0) ? -1.f : pr;
    int sel0, sel1, sel2; float sw0, sw1, sw2;
#pragma unroll
    for (int k = 0; k < 3; k++) {
      float bv = val; int bi = e;
#pragma unroll
      for (int off = 8; off > 0; off >>= 1) {
        float ov = __shfl_xor(bv, off);
        int   oi = __shfl_xor(bi, off);
        if (ov > bv || (ov == bv && oi < bi)) { bv = ov; bi = oi; }
      }
      if (k == 0) { sel0 = bi; sw0 = bv; }
      else if (k == 1) { sel1 = bi; sw1 = bv; }
      else { sel2 = bi; sw2 = bv; }
      if (e == bi) val = -1.f;
    }
    // ---- block-aggregated bucket insert: one atomic per expert per block ---
    __shared__ int sse[16];
    __shared__ unsigned smask[16];
    __shared__ int sbase[16];
    if (lane < 4) {
      int se; float swt;
      if (lane == 0)      { se = 0;    swt = 1.0f; }
      else if (lane == 1) { se = sel0; swt = sw0; }
      else if (lane == 2) { se = sel1; swt = sw1; }
      else                { se = sel2; swt = sw2; }
      int slot = wave * 4 + lane;
      sse[slot] = se;
      int pidx = bid * 16 + slot;
      psel[pidx] = se; pw[pidx] = swt;
    }
    __syncthreads();
    if (tid < 16) {
      unsigned mask = 0;
#pragma unroll
      for (int s2 = 0; s2 < 16; s2++) mask |= (sse[s2] == tid) ? (1u << s2) : 0u;
      smask[tid] = mask;
      int c = __popc(mask);
      sbase[tid] = c ? atomicAdd(&cnt[tid], c) : 0;
    }
    __syncthreads();
    if (tid < 16) {
      int e2 = sse[tid];
      unsigned mask = smask[e2];
      int rank = __popc(mask & ((1u << tid) - 1u));
      plist[e2 * T_TOK + sbase[e2] + rank] = bid * 16 + tid;
    }
  } else if (bid < NGATE + NX) {
    if (!isbf) conv8(x32, xC, ((size_t)(bid - NGATE) * 256 + tid) * 8);
  } else if (bid < NGATE + NX + NB) {
    if (!isbf) {
      size_t g = (size_t)(bid - NGATE - NX) * 256 + tid;   // [0, 3072)
      size_t i = g * 8;
      conv8(fc1bF, dfc1b, i);
      conv8(lnwF,  dlnw,  i);
      conv8(lnbF,  dlnb,  i);
      if (g < 1536) conv8(fc2bF, dfc2b, i);
    }
  } else {
    if (!isbf) {
      int cb = bid - (NGATE + NX + NB);        // 0..2303, 4 chunks each
#pragma unroll
      for (int it = 0; it < 4; it++)
        conv8(w1F, wsW1, ((size_t)(cb * 4 + it) * 256 + tid) * 8);
    }
  }
}

// ---------------- K2/K4: grouped GEMM, NATIVE-layout B via tr-reads ---------
// Block tile 128x128, BK=64, single LDS buffer. 4 waves as 2x2 -> 64x64.
// XCD-affinity swizzle: all 16 m-tile blocks sharing weight slice P=(e,ns)
// carry the same bx%8 -> same XCD -> the 196KB B slice stays L2-resident
// across its consumers. P = (bx>>7)*8 + (bx&7), mt = (bx>>3)&15; bijective
// since NE*NSP (192 / 96) is divisible by 8; experts' m-tile load spreads
// evenly across XCDs (expert P-ranges span all residues).
// A: gathered rows, k-contiguous, XOR-swizzled source+read.
// B: native [e][KDIM][NDIM] staged subtiled via permuted per-lane global
//   source + linear LDS dest; consumed with ds_read_b64_tr_b16
//   (vaddr = sB + ks*8192 + quad*2048 + (wave&1)*512 + nt*128 + m16*8,
//    second half at +1024).
// CONVW2: extra trailing blocks convert fc2_w f32->bf16 concurrently with the
// fc1 GEMM (fc2 consumes it only after ln -> stream order safe).
template<int KDIM, int NDIM, bool GELU, bool HASBIAS, bool AROWDIV4, bool OUTF32,
         bool CONVW2>
__global__ __launch_bounds__(256) void moe_gemm(
    const unsigned short* __restrict__ AO, const unsigned short* __restrict__ AC,
    const unsigned short* __restrict__ BO, const unsigned short* __restrict__ BC,
    const unsigned short* __restrict__ biasO, const unsigned short* __restrict__ biasC,
    const float* __restrict__ w2F, unsigned short* __restrict__ w2D,
    const int* __restrict__ flag,
    const int* __restrict__ cnt, const int* __restrict__ plist,
    unsigned short* __restrict__ outB, float* __restrict__ outF)
{
  const int NSP = NDIM / 128;
  int bx  = blockIdx.x;
  int tid = threadIdx.x;
  if (CONVW2) {
    const int nblk = NE * 16 * NSP;
    if (bx >= nblk) {
      if (!*flag) {
        int cb = bx - nblk;                    // 0..NW2B-1, 4 chunks each
#pragma unroll
        for (int it = 0; it < 4; it++)
          conv8(w2F, w2D, ((size_t)(cb * 4 + it) * 256 + tid) * 8);
      }
      return;
    }
  }
  // XCD-affinity remap (bijective): same (e,ns) -> same bx%8 -> same XCD
  int P   = (bx >> 7) * 8 + (bx & 7);
  int mt  = (bx >> 3) & 15;
  int e   = P / NSP;
  int ns  = P % NSP;
  int count = cnt[e];
  if (mt * 128 >= count) return;
  const unsigned short* Abase   = (*flag) ? AO : AC;
  const unsigned short* Bbase   = (*flag) ? BO : BC;
  const unsigned short* biasAll = (*flag) ? biasO : biasC;

  __shared__ __align__(16) unsigned short sA[128 * 64];
  __shared__ __align__(16) unsigned short sB[64 * 128];   // subtiled
  __shared__ int sp[128];

  if (tid < 128) {
    int rg  = mt * 128 + tid;
    int idx = rg < count ? rg : count - 1;    // duplicate last row (pad)
    sp[tid] = plist[e * T_TOK + idx];
  }
  __syncthreads();

  int lane = tid & 63;
  int wave = tid >> 6;
  int n0   = ns * 128;

  // --- A staging (XOR chunk swizzle on source + read) ---
  int lrow  = lane >> 3;
  int lsch  = (lane & 7) ^ lrow;
  const unsigned short* ag[4];
  int loffA[4];
#pragma unroll
  for (int s = 0; s < 4; s++) {
    int r  = wave * 32 + s * 8;
    int p  = sp[r + lrow];
    ag[s] = Abase + (size_t)(AROWDIV4 ? (p >> 2) : p) * KDIM + lsch * 8;
    loffA[s] = r * 64;
  }

  // --- B staging (native layout, subtiled via pre-permuted source) ---
  int bk = (lane >> 1) & 3;
  int bn = (lane >> 3) * 16 + (lane & 1) * 8;
  const unsigned short* bg[4];
  int loffB[4];
#pragma unroll
  for (int s = 0; s < 4; s++) {
    int krow = wave * 16 + s * 4 + bk;         // tile-local k row
    bg[s] = Bbase + ((size_t)e * KDIM + krow) * NDIM + n0 + bn;
    loffB[s] = (wave * 4 + s) * 512;           // elems (kb block = 512 elems)
  }

  int m16  = lane & 15;
  int quad = lane >> 4;
  int wm   = (wave >> 1) * 64;
  int wn   = (wave & 1) * 64;
  int rsw  = (m16 & 7);
  unsigned trB = ldsaddr(sB)
               + (unsigned)(quad * 2048 + (wave & 1) * 512 + m16 * 8);

  floatx4 acc[4][4];
#pragma unroll
  for (int i = 0; i < 4; i++)
#pragma unroll
    for (int j = 0; j < 4; j++) acc[i][j] = (floatx4){0.f, 0.f, 0.f, 0.f};

  for (int k0 = 0; k0 < KDIM; k0 += 64) {
    if (k0) __syncthreads();                   // prev iter's LDS reads done
#pragma unroll
    for (int s = 0; s < 4; s++) gload16(ag[s] + k0, sA + loffA[s]);
#pragma unroll
    for (int s = 0; s < 4; s++) gload16(bg[s] + (size_t)k0 * NDIM, sB + loffB[s]);
    __syncthreads();                           // vmcnt(0) drain: tile landed
#pragma unroll
    for (int ks = 0; ks < 2; ks++) {
      int ch = ((ks * 4 + quad) ^ rsw) * 8;
      short8 af[4];
#pragma unroll
      for (int m = 0; m < 4; m++)
        af[m] = *(const short8*)(sA + (wm + m * 16 + m16) * 64 + ch);
      short8 bf[4];
#pragma unroll
      for (int nt = 0; nt < 4; nt++) {
        union { short4v h[2]; short8 w; } u;
        u.h[0] = tr8(trB + (unsigned)(ks * 8192 + nt * 128));
        u.h[1] = tr8(trB + (unsigned)(ks * 8192 + 1024 + nt * 128));
        bf[nt] = u.w;
      }
      asm volatile("s_waitcnt lgkmcnt(0)" ::: "memory");
      __builtin_amdgcn_sched_barrier(0);
#pragma unroll
      for (int m = 0; m < 4; m++)
#pragma unroll
        for (int n = 0; n < 4; n++)
          acc[m][n] = __builtin_amdgcn_mfma_f32_16x16x32_bf16(af[m], bf[n], acc[m][n], 0, 0, 0);
    }
  }

  // epilogue: C/D col = lane&15 (-> n dim), row = quad*4 + reg (-> m dim)
#pragma unroll
  for (int m = 0; m < 4; m++) {
#pragma unroll
    for (int r = 0; r < 4; r++) {
      int row_local = wm + m * 16 + quad * 4 + r;
      int rg = mt * 128 + row_local;
      if (rg < count) {
        int p = sp[row_local];
#pragma unroll
        for (int n = 0; n < 4; n++) {
          int col = n0 + wn + n * 16 + m16;
          float v = acc[m][n][r];
          if (HASBIAS) v += bf2f(biasAll[e * NDIM + col]);
          if (GELU)    v = 0.5f * v * (1.f + erff(v * 0.70710678118654752f));
          if (OUTF32) outF[(size_t)p * NDIM + col] = v;
          else        outB[(size_t)p * NDIM + col] = f2bf(v);
        }
      }
    }
  }
}

// ---------------- K3: LayerNorm per pair, combine weight folded in ----------
__global__ __launch_bounds__(256) void ln_kernel(
    unsigned short* __restrict__ Hbuf,
    const unsigned short* __restrict__ lnwO, const unsigned short* __restrict__ lnwC,
    const unsigned short* __restrict__ lnbO, const unsigned short* __restrict__ lnbC,
    const int* __restrict__ psel, const float* __restrict__ pw,
    const int* __restrict__ flag)
{
  int p = blockIdx.x;
  int tid = threadIdx.x;
  int e = psel[p];
  int isbf = *flag;
  const unsigned short* lnw = isbf ? lnwO : lnwC;
  const unsigned short* lnb = isbf ? lnbO : lnbC;
  unsigned short* hr = Hbuf + (size_t)p * H_FFN;
  bool act = tid < 192;
  float v[8];
  float s = 0.f, sq = 0.f;
  if (act) {
    ushort8 hv = *(const ushort8*)(hr + tid * 8);
#pragma unroll
    for (int j = 0; j < 8; j++) { v[j] = bf2f(hv[j]); s += v[j]; sq += v[j] * v[j]; }
  }
#pragma unroll
  for (int off = 32; off > 0; off >>= 1) {
    s  += __shfl_down(s, off);
    sq += __shfl_down(sq, off);
  }
  __shared__ float red[8];
  int wave = tid >> 6, lane = tid & 63;
  if (lane == 0) { red[wave * 2] = s; red[wave * 2 + 1] = sq; }
  __syncthreads();
  __shared__ float mv[2];
  if (tid == 0) {
    float S = 0.f, Q = 0.f;
    for (int w = 0; w < 4; w++) { S += red[w * 2]; Q += red[w * 2 + 1]; }
    float mu  = S * (1.f / H_FFN);
    float var = Q * (1.f / H_FFN) - mu * mu;
    mv[0] = mu; mv[1] = rsqrtf(var + 1e-5f);
  }
  __syncthreads();
  if (act) {
    float mu = mv[0], rstd = mv[1];
    float w = pw[p];
    ushort8 lw = *(const ushort8*)(lnw + e * H_FFN + tid * 8);
    ushort8 lb = *(const ushort8*)(lnb + e * H_FFN + tid * 8);
    ushort8 o;
#pragma unroll
    for (int j = 0; j < 8; j++)
      o[j] = f2bf(((v[j] - mu) * rstd * bf2f(lw[j]) + bf2f(lb[j])) * w);
    *(ushort8*)(hr + tid * 8) = o;
  }
}

// ---------------- K5: sum 4 pair outputs + weighted fc2 bias ----------------
__global__ __launch_bounds__(192) void combine_kernel(
    const float* __restrict__ Y,
    const unsigned short* __restrict__ b2O, const unsigned short* __restrict__ b2C,
    const int* __restrict__ psel, const float* __restrict__ pw,
    unsigned short* __restrict__ out16, float* __restrict__ out32,
    const int* __restrict__ flag)
{
  int t = blockIdx.x;
  int tid = threadIdx.x;                       // 192 threads, 192*4 = 768
  int isbf = *flag;
  const unsigned short* b2 = isbf ? b2O : b2C;
  int e1 = psel[t * 4 + 1], e2 = psel[t * 4 + 2], e3 = psel[t * 4 + 3];
  float w1 = pw[t * 4 + 1], w2 = pw[t * 4 + 2], w3 = pw[t * 4 + 3];
  int d = tid * 4;
  const float* Yb = Y + (size_t)t * 4 * D_EMB + d;
  floatx4 y0 = *(const floatx4*)(Yb);
  floatx4 y1 = *(const floatx4*)(Yb + D_EMB);
  floatx4 y2 = *(const floatx4*)(Yb + 2 * D_EMB);
  floatx4 y3 = *(const floatx4*)(Yb + 3 * D_EMB);
  ushort4v b0 = *(const ushort4v*)(b2 + d);
  ushort4v bb1 = *(const ushort4v*)(b2 + e1 * D_EMB + d);
  ushort4v bb2 = *(const ushort4v*)(b2 + e2 * D_EMB + d);
  ushort4v bb3 = *(const ushort4v*)(b2 + e3 * D_EMB + d);
  if (isbf) {
    ushort4v o;
#pragma unroll
    for (int j = 0; j < 4; j++) {
      float a = y0[j] + y1[j] + y2[j] + y3[j] + bf2f(b0[j])
              + w1 * bf2f(bb1[j]) + w2 * bf2f(bb2[j]) + w3 * bf2f(bb3[j]);
      o[j] = f2bf(a);
    }
    *(ushort4v*)(out16 + (size_t)t * D_EMB + d) = o;
  } else {
    floatx4 o;
#pragma unroll
    for (int j = 0; j < 4; j++)
      o[j] = y0[j] + y1[j] + y2[j] + y3[j] + bf2f(b0[j])
           + w1 * bf2f(bb1[j]) + w2 * bf2f(bb2[j]) + w3 * bf2f(bb3[j]);
    *(floatx4*)(out32 + (size_t)t * D_EMB + d) = o;
  }
}

extern "C" void kernel_launch(void* const* d_in, const int* in_sizes, int n_in,
                              void* d_out, int out_size, void* d_ws, size_t ws_size,
                              hipStream_t stream)
{
  (void)in_sizes; (void)n_in; (void)out_size; (void)ws_size;
  char* ws = (char*)d_ws;
  int*   cnt   = (int*)ws;                                 // 16 ints
  int*   plist = (int*)(ws + 256);                         // 16*2048 ints
  int*   psel  = (int*)(ws + 131328);                      // 8192 ints
  float* pw    = (float*)(ws + 164096);                    // 8192 f32
  int*   flag  = (int*)(ws + 196864);
  unsigned short* fc1bC = (unsigned short*)(ws + 197120);  // 24576 bf16
  unsigned short* lnwC  = (unsigned short*)(ws + 246272);
  unsigned short* lnbC  = (unsigned short*)(ws + 295424);
  unsigned short* fc2bC = (unsigned short*)(ws + 344576);  // 12288 bf16
  unsigned short* xC    = (unsigned short*)(ws + 524288);  // 1572864 bf16
  unsigned short* Hbuf  = (unsigned short*)(ws + 3670016); // 8192*1536 bf16
  float*          Ybuf  = (float*)(ws + 28835840);         // 8192*768 f32
  unsigned short* wsW1  = (unsigned short*)(ws + 54001664);// [16][768][1536] bf16
  unsigned short* wsW2  = (unsigned short*)(ws + 91750400);// [16][1536][768] bf16

  hipMemsetAsync(cnt, 0, 64, stream);                      // zero expert counters

  prep_kernel<<<NGATE + NX + NB + NW1B, 256, 0, stream>>>(
      (const unsigned int*)d_in[0],
      (const unsigned short*)d_in[0], (const float*)d_in[0],
      (const unsigned short*)d_in[1], (const float*)d_in[1],
      (const unsigned short*)d_in[2], (const float*)d_in[2],
      (const float*)d_in[3],
      (const float*)d_in[4], (const float*)d_in[5],
      (const float*)d_in[6], (const float*)d_in[8],
      xC, wsW1,
      fc1bC, lnwC, lnbC, fc2bC,
      flag, psel, pw, cnt, plist);

  moe_gemm<D_EMB, H_FFN, true, true, true, false, true>
      <<<NE * 16 * (H_FFN / 128) + NW2B, 256, 0, stream>>>(
      (const unsigned short*)d_in[0], xC,
      (const unsigned short*)d_in[3], wsW1,
      (const unsigned short*)d_in[4], fc1bC,
      (const float*)d_in[7], wsW2,
      flag, cnt, plist, Hbuf, nullptr);

  ln_kernel<<<NPAIR, 256, 0, stream>>>(
      Hbuf,
      (const unsigned short*)d_in[5], lnwC,
      (const unsigned short*)d_in[6], lnbC,
      psel, pw, flag);

  moe_gemm<H_FFN, D_EMB, false, false, false, true, false>
      <<<NE * 16 * (D_EMB / 128), 256, 0, stream>>>(
      Hbuf, Hbuf,
      (const unsigned short*)d_in[7], wsW2,
      nullptr, nullptr,
      nullptr, nullptr,
      flag, cnt, plist, nullptr, Ybuf);

  combine_kernel<<<T_TOK, 192, 0, stream>>>(
      Ybuf,
      (const unsigned short*)d_in[8], fc2bC,
      psel, pw,
      (unsigned short*)d_out, (float*)d_out, flag);
}